// Round 10
// baseline (1241.229 us; speedup 1.0000x reference)
//
#include <hip/hip_runtime.h>

// Problem constants (fixed-shape: B=8192, IN=1024, N=4096, K=409)
#define BATCH 8192
#define INF   1024
#define NF    4096
#define BN_EPS 1e-5
#define NT    96     // K' tiles: 6 segments * 16 tiles of 64

typedef __attribute__((ext_vector_type(8))) short short8v;
typedef __attribute__((ext_vector_type(4))) float f32x4;

#define FENCE asm volatile("" ::: "memory")
#define BARRIER do { FENCE; __builtin_amdgcn_s_barrier(); FENCE; } while (0)

// ---------------------------------------------------------------------------
// Kernel 1: zero the f64 stats accumulators (2*4096 doubles)
// ---------------------------------------------------------------------------
__global__ void zero_ws(double* __restrict__ p) {
    p[blockIdx.x * 256 + threadIdx.x] = 0.0;
}

// ---------------------------------------------------------------------------
// Exact 3-way bf16 truncation split: x == bf16(h0)+bf16(h1)+bf16(h2) EXACTLY.
// ---------------------------------------------------------------------------
__device__ __forceinline__ void split3(float x, ushort& h0, ushort& h1, ushort& h2) {
    const unsigned u0 = __float_as_uint(x) & 0xFFFF0000u;
    const float    r1 = x - __uint_as_float(u0);
    const unsigned u1 = __float_as_uint(r1) & 0xFFFF0000u;
    const float    r2 = r1 - __uint_as_float(u1);
    h0 = (ushort)(u0 >> 16);
    h1 = (ushort)(u1 >> 16);
    h2 = (ushort)(__float_as_uint(r2) >> 16);
}

// ---------------------------------------------------------------------------
// Pre-split X / masked-W into 3 bf16 planes, stored PRE-SWIZZLED:
// source 16B-chunk j of row goes to flat unit (j&~7) | ((j&7) ^ (row&7)).
// global_load_lds stages linearly; swizzled ds_reads are conflict-free
// (rule #21: inverse-swizzled source + same-involution read). Verified R9:
// SQ_LDS_BANK_CONFLICT == 0.
// ---------------------------------------------------------------------------
__global__ __launch_bounds__(256) void split_x_kernel(
    const float* __restrict__ X, ushort* __restrict__ xs)
{
    const int tid = blockIdx.x * 256 + threadIdx.x;
    const int row = tid >> 7;            // 128 units per row
    const int j   = tid & 127;           // source chunk
    const size_t LS = (size_t)BATCH * INF;
    const float* src = X + (size_t)row * INF + j * 8;
    const float4 v0 = *(const float4*)(src);
    const float4 v1 = *(const float4*)(src + 4);
    const float v[8] = {v0.x, v0.y, v0.z, v0.w, v1.x, v1.y, v1.z, v1.w};
    short8v s0, s1, s2;
#pragma unroll
    for (int i = 0; i < 8; ++i) {
        ushort h0, h1, h2;
        split3(v[i], h0, h1, h2);
        s0[i] = (short)h0; s1[i] = (short)h1; s2[i] = (short)h2;
    }
    const int dj = (j & ~7) | ((j & 7) ^ (row & 7));
    const size_t du = ((size_t)row * 128 + dj) * 8;
    *(short8v*)&xs[du]          = s0;
    *(short8v*)&xs[du + LS]     = s1;
    *(short8v*)&xs[du + 2 * LS] = s2;
}

__global__ __launch_bounds__(256) void split_w_kernel(
    const float* __restrict__ W, const int* __restrict__ Mk, ushort* __restrict__ wsp)
{
    const int tid = blockIdx.x * 256 + threadIdx.x;
    const int row = tid >> 7;
    const int j   = tid & 127;
    const size_t LS = (size_t)NF * INF;
    const float* src = W + (size_t)row * INF + j * 8;
    const int*   msk = Mk + (size_t)row * INF + j * 8;
    const float4 v0 = *(const float4*)(src);
    const float4 v1 = *(const float4*)(src + 4);
    const int4   m0 = *(const int4*)(msk);
    const int4   m1 = *(const int4*)(msk + 4);
    const float v[8] = {v0.x * (float)m0.x, v0.y * (float)m0.y,
                        v0.z * (float)m0.z, v0.w * (float)m0.w,
                        v1.x * (float)m1.x, v1.y * (float)m1.y,
                        v1.z * (float)m1.z, v1.w * (float)m1.w};
    short8v s0, s1, s2;
#pragma unroll
    for (int i = 0; i < 8; ++i) {
        ushort h0, h1, h2;
        split3(v[i], h0, h1, h2);
        s0[i] = (short)h0; s1[i] = (short)h1; s2[i] = (short)h2;
    }
    const int dj = (j & ~7) | ((j & 7) ^ (row & 7));
    const size_t du = ((size_t)row * 128 + dj) * 8;
    *(short8v*)&wsp[du]          = s0;
    *(short8v*)&wsp[du + LS]     = s1;
    *(short8v*)&wsp[du + 2 * LS] = s2;
}

// ---------------------------------------------------------------------------
// direct global->LDS 16B staging
// ---------------------------------------------------------------------------
__device__ __forceinline__ void gload16(const ushort* g, ushort* l) {
    __builtin_amdgcn_global_load_lds(
        (const __attribute__((address_space(1))) void*)g,
        (__attribute__((address_space(3))) void*)l, 16, 0, 0);
}

// ---------------------------------------------------------------------------
// Kernel 2 (fast path): deep-pipelined MFMA GEMM over the 6-plane product,
// viewed as one bf16 GEMM with K' = 6144 (segments small-first:
// A[2,1,0,1,0,0] x B[0,1,2,0,1,0]).
// BM=256, BN=128, BK=64, 512 thr = 8 waves (2M x 4N), per-wave 128x32.
// R10 changes vs R9 (schedule only, numerics identical):
//  - __launch_bounds__(512, 2): LDS already caps at 1 block/CU (2 waves/
//    SIMD), so let the allocator use 256 VGPRs -> 192-reg acc+mst state
//    stays in registers (R9's 128-cap spilled it; MfmaUtil 31%).
//  - 2 phases/tile x 16 MFMAs, 3 barriers/tile (was 8 barriers, 8 MFMAs
//    per interval -> barrier-latency-dominated).
// Triple-buffered LDS (144KB dynamic), tile t+2 staged via global_load_lds,
// counted vmcnt(6), raw s_barrier, setprio around MFMA. f32 acc drained
// into f64 shadow every 2 tiles (exact master; passing numerics R9).
// ---------------------------------------------------------------------------
__global__ __launch_bounds__(512, 2) void gemm_mfma_8ph(
    const ushort* __restrict__ Xs, const ushort* __restrict__ Wsp,
    const float* __restrict__ bias, float* __restrict__ Y)
{
    extern __shared__ ushort sm[];   // A: 3 x 16384, B(+49152): 3 x 8192 ushorts
    const size_t LSX = (size_t)BATCH * INF;
    const size_t LSW = (size_t)NF * INF;

    const int t    = threadIdx.x;
    const int row0 = blockIdx.y * 256;
    const int col0 = blockIdx.x * 128;

    const int l   = t & 63;
    const int l15 = l & 15;
    const int hi  = l >> 4;
    const int wid = t >> 6;
    const int wm  = wid >> 2;        // 0..1 -> M offset wm*128
    const int wnw = wid & 3;         // 0..3 -> N offset wnw*32

    const int srow_hi = t >> 3;      // 0..63: row within a staging round
    const int su      = t & 7;       // unit within row-group
    const int wbase   = (t & ~63);   // wave-uniform lane base

    f32x4  acc[8][2];
    double mst[8][2][4];
#pragma unroll
    for (int f = 0; f < 8; ++f)
#pragma unroll
        for (int nf = 0; nf < 2; ++nf) {
            acc[f][nf] = (f32x4){0.f, 0.f, 0.f, 0.f};
#pragma unroll
            for (int r = 0; r < 4; ++r) mst[f][nf][r] = 0.0;
        }

    // ---- prologue: stage tiles 0 and 1 (segment 0: Aplane=2, Bplane=0) ----
    {
        const ushort* Apl = Xs + 2 * LSX;
        const ushort* Bpl = Wsp;
#pragma unroll
        for (int tt = 0; tt < 2; ++tt) {
            ushort* Abuf = sm + tt * 16384;
            ushort* Bbuf = sm + 49152 + tt * 8192;
#pragma unroll
            for (int r = 0; r < 4; ++r)
                gload16(Apl + ((size_t)(row0 + r * 64 + srow_hi) * 128 + tt * 8 + su) * 8,
                        Abuf + (size_t)(r * 512 + wbase) * 8);
#pragma unroll
            for (int r = 0; r < 2; ++r)
                gload16(Bpl + ((size_t)(col0 + r * 64 + srow_hi) * 128 + tt * 8 + su) * 8,
                        Bbuf + (size_t)(r * 512 + wbase) * 8);
        }
    }
    asm volatile("s_waitcnt vmcnt(6)" ::: "memory");
    BARRIER;

    // ---- main loop over 96 K'-tiles ----
    int bsel = 0;
    for (int tt = 0; tt < NT; ++tt) {
        const int t2   = tt + 2;
        const int s2   = t2 >> 4;
        const int ktl2 = t2 & 15;
        const int ap2 = (s2 == 0) ? 2 : ((s2 == 1 || s2 == 3) ? 1 : 0);
        const int bp2 = (s2 == 2) ? 2 : ((s2 == 1 || s2 == 4) ? 1 : 0);
        const ushort* Apl2 = Xs + (size_t)ap2 * LSX;
        const ushort* Bpl2 = Wsp + (size_t)bp2 * LSW;
        const int b2 = (bsel >= 1) ? bsel - 1 : 2;    // (bsel+2)%3
        ushort* A2 = sm + b2 * 16384;
        ushort* B2 = sm + 49152 + b2 * 8192;
        const ushort* Abuf = sm + bsel * 16384;
        const ushort* Bbuf = sm + 49152 + bsel * 8192;

        short8v Bf[2][2];

        // ---- 2 phases x 16 MFMAs ----
#pragma unroll
        for (int ph = 0; ph < 2; ++ph) {
            short8v Af[4][2];
#pragma unroll
            for (int ff = 0; ff < 4; ++ff) {
                const int ra = wm * 128 + (ph * 4 + ff) * 16 + l15;
#pragma unroll
                for (int ks = 0; ks < 2; ++ks)
                    Af[ff][ks] = *(const short8v*)&Abuf[ra * 64 + (((ks * 4 + hi) ^ (ra & 7)) << 3)];
            }
            if (ph == 0) {
#pragma unroll
                for (int nf = 0; nf < 2; ++nf) {
                    const int rb = wnw * 32 + nf * 16 + l15;
#pragma unroll
                    for (int ks = 0; ks < 2; ++ks)
                        Bf[nf][ks] = *(const short8v*)&Bbuf[rb * 64 + (((ks * 4 + hi) ^ (rb & 7)) << 3)];
                }
            }
            // stage half of tile t+2 (2 A-loads + 1 B-load per phase)
            if (t2 < NT) {
#pragma unroll
                for (int rr = 0; rr < 2; ++rr) {
                    const int r = ph * 2 + rr;
                    gload16(Apl2 + ((size_t)(row0 + r * 64 + srow_hi) * 128 + ktl2 * 8 + su) * 8,
                            A2 + (size_t)(r * 512 + wbase) * 8);
                }
                gload16(Bpl2 + ((size_t)(col0 + ph * 64 + srow_hi) * 128 + ktl2 * 8 + su) * 8,
                        B2 + (size_t)(ph * 512 + wbase) * 8);
            }
            BARRIER;
            __builtin_amdgcn_s_setprio(1);
#pragma unroll
            for (int ff = 0; ff < 4; ++ff)
#pragma unroll
                for (int nf = 0; nf < 2; ++nf) {
                    f32x4 c = acc[ph * 4 + ff][nf];
                    c = __builtin_amdgcn_mfma_f32_16x16x32_bf16(Af[ff][0], Bf[nf][0], c, 0, 0, 0);
                    c = __builtin_amdgcn_mfma_f32_16x16x32_bf16(Af[ff][1], Bf[nf][1], c, 0, 0, 0);
                    acc[ph * 4 + ff][nf] = c;
                }
            __builtin_amdgcn_s_setprio(0);
        }

        // ---- tile end: drain, counted wait, lockstep barrier ----
        if (tt & 1) {   // drain every 2 K-tiles into f64 shadow (exact)
#pragma unroll
            for (int f = 0; f < 8; ++f)
#pragma unroll
                for (int nf = 0; nf < 2; ++nf) {
#pragma unroll
                    for (int r = 0; r < 4; ++r) mst[f][nf][r] += (double)acc[f][nf][r];
                    acc[f][nf] = (f32x4){0.f, 0.f, 0.f, 0.f};
                }
        }
        if (tt < NT - 2)       { asm volatile("s_waitcnt vmcnt(6)" ::: "memory"); }
        else if (tt == NT - 2) { asm volatile("s_waitcnt vmcnt(0)" ::: "memory"); }
        BARRIER;
        bsel = (bsel == 2) ? 0 : bsel + 1;
    }

    // ---- epilogue: bias in f64, store f32 ----
#pragma unroll
    for (int f = 0; f < 8; ++f)
#pragma unroll
        for (int nf = 0; nf < 2; ++nf) {
            const int colc = col0 + wnw * 32 + nf * 16 + l15;
            const double bb = (double)bias[colc];
#pragma unroll
            for (int r = 0; r < 4; ++r) {
                const int roww = row0 + wm * 128 + f * 16 + hi * 4 + r;
                Y[(size_t)roww * NF + colc] = (float)(mst[f][nf][r] + bb);
            }
        }
}

// ---------------------------------------------------------------------------
// Kernel 2 (fallback, ws too small): in-kernel split, 6 products (R7 code).
// ---------------------------------------------------------------------------
__global__ __launch_bounds__(512) void gemm_mfma_split(
    const float* __restrict__ X, const float* __restrict__ W,
    const int* __restrict__ Mk, const float* __restrict__ bias,
    float* __restrict__ Y)
{
    __shared__ __align__(16) ushort a0s[128 * 40];
    __shared__ __align__(16) ushort a1s[128 * 40];
    __shared__ __align__(16) ushort a2s[128 * 40];
    __shared__ __align__(16) ushort b0s[128 * 40];
    __shared__ __align__(16) ushort b1s[128 * 40];
    __shared__ __align__(16) ushort b2s[128 * 40];

    const int t = threadIdx.x;
    const int row0 = blockIdx.y * 128;
    const int col0 = blockIdx.x * 128;
    const int srow = t >> 2;
    const int skb  = (t & 3) * 8;

    const float* Xp = X + (size_t)(row0 + srow) * INF + skb;
    const float* Wp = W + (size_t)(col0 + srow) * INF + skb;
    const int*   Mp = Mk + (size_t)(col0 + srow) * INF + skb;

    const int l   = t & 63;
    const int l15 = l & 15;
    const int hi  = l >> 4;
    const int wid = t >> 6;
    const int wm  = wid >> 1;
    const int wn  = wid & 1;

    f32x4  acc[2][4];
    double sh[2][4][4];
#pragma unroll
    for (int mf = 0; mf < 2; ++mf)
#pragma unroll
        for (int nf = 0; nf < 4; ++nf) {
            acc[mf][nf] = (f32x4){0.f, 0.f, 0.f, 0.f};
#pragma unroll
            for (int r = 0; r < 4; ++r) sh[mf][nf][r] = 0.0;
        }

    float4 xA0 = *(const float4*)(Xp);
    float4 xA1 = *(const float4*)(Xp + 4);
    float4 wB0 = *(const float4*)(Wp);
    float4 wB1 = *(const float4*)(Wp + 4);
    int4   mB0 = *(const int4*)(Mp);
    int4   mB1 = *(const int4*)(Mp + 4);

    for (int k0 = 0; k0 < INF; k0 += 32) {
        __syncthreads();
        {
            const float v[8] = {xA0.x, xA0.y, xA0.z, xA0.w, xA1.x, xA1.y, xA1.z, xA1.w};
            short8v s0, s1, s2;
#pragma unroll
            for (int i = 0; i < 8; ++i) {
                ushort h0, h1, h2;
                split3(v[i], h0, h1, h2);
                s0[i] = (short)h0; s1[i] = (short)h1; s2[i] = (short)h2;
            }
            const int off = srow * 40 + skb;
            *(short8v*)&a0s[off] = s0;
            *(short8v*)&a1s[off] = s1;
            *(short8v*)&a2s[off] = s2;
        }
        {
            const float wv[8] = {wB0.x * (float)mB0.x, wB0.y * (float)mB0.y,
                                 wB0.z * (float)mB0.z, wB0.w * (float)mB0.w,
                                 wB1.x * (float)mB1.x, wB1.y * (float)mB1.y,
                                 wB1.z * (float)mB1.z, wB1.w * (float)mB1.w};
            short8v s0, s1, s2;
#pragma unroll
            for (int i = 0; i < 8; ++i) {
                ushort h0, h1, h2;
                split3(wv[i], h0, h1, h2);
                s0[i] = (short)h0; s1[i] = (short)h1; s2[i] = (short)h2;
            }
            const int off = srow * 40 + skb;
            *(short8v*)&b0s[off] = s0;
            *(short8v*)&b1s[off] = s1;
            *(short8v*)&b2s[off] = s2;
        }
        __syncthreads();

        if (k0 + 32 < INF) {
            const int kn = k0 + 32;
            xA0 = *(const float4*)(Xp + kn);
            xA1 = *(const float4*)(Xp + kn + 4);
            wB0 = *(const float4*)(Wp + kn);
            wB1 = *(const float4*)(Wp + kn + 4);
            mB0 = *(const int4*)(Mp + kn);
            mB1 = *(const int4*)(Mp + kn + 4);
        }

        short8v A[2][3], B[4][3];
#pragma unroll
        for (int mf = 0; mf < 2; ++mf) {
            const int roff = (wm * 32 + mf * 16 + l15) * 40 + hi * 8;
            A[mf][0] = *(const short8v*)&a0s[roff];
            A[mf][1] = *(const short8v*)&a1s[roff];
            A[mf][2] = *(const short8v*)&a2s[roff];
        }
#pragma unroll
        for (int nf = 0; nf < 4; ++nf) {
            const int roff = (wn * 64 + nf * 16 + l15) * 40 + hi * 8;
            B[nf][0] = *(const short8v*)&b0s[roff];
            B[nf][1] = *(const short8v*)&b1s[roff];
            B[nf][2] = *(const short8v*)&b2s[roff];
        }

#pragma unroll
        for (int mf = 0; mf < 2; ++mf)
#pragma unroll
            for (int nf = 0; nf < 4; ++nf) {
                f32x4 c = acc[mf][nf];
                c = __builtin_amdgcn_mfma_f32_16x16x32_bf16(A[mf][0], B[nf][0], c, 0, 0, 0);
                c = __builtin_amdgcn_mfma_f32_16x16x32_bf16(A[mf][0], B[nf][1], c, 0, 0, 0);
                c = __builtin_amdgcn_mfma_f32_16x16x32_bf16(A[mf][1], B[nf][0], c, 0, 0, 0);
                c = __builtin_amdgcn_mfma_f32_16x16x32_bf16(A[mf][0], B[nf][2], c, 0, 0, 0);
                c = __builtin_amdgcn_mfma_f32_16x16x32_bf16(A[mf][1], B[nf][1], c, 0, 0, 0);
                c = __builtin_amdgcn_mfma_f32_16x16x32_bf16(A[mf][2], B[nf][0], c, 0, 0, 0);
                acc[mf][nf] = c;
            }

        if (k0 & 32) {
#pragma unroll
            for (int mf = 0; mf < 2; ++mf)
#pragma unroll
                for (int nf = 0; nf < 4; ++nf) {
#pragma unroll
                    for (int r = 0; r < 4; ++r) sh[mf][nf][r] += (double)acc[mf][nf][r];
                    acc[mf][nf] = (f32x4){0.f, 0.f, 0.f, 0.f};
                }
        }
    }

#pragma unroll
    for (int mf = 0; mf < 2; ++mf)
#pragma unroll
        for (int nf = 0; nf < 4; ++nf) {
            const int col = col0 + wn * 64 + nf * 16 + l15;
            const double bb = (double)bias[col];
#pragma unroll
            for (int r = 0; r < 4; ++r) {
                const int row = row0 + wm * 32 + mf * 16 + hi * 4 + r;
                Y[(size_t)row * NF + col] = (float)(sh[mf][nf][r] + bb);
            }
        }
}

// ---------------------------------------------------------------------------
// Kernel 3: per-column partial sums (f64) over 256-row chunks
// ---------------------------------------------------------------------------
__global__ __launch_bounds__(256) void stats_partial(
    const float* __restrict__ Y, double* __restrict__ dsum, double* __restrict__ dsqs)
{
    const int col = blockIdx.x * 256 + threadIdx.x;
    const int r0  = blockIdx.y * 256;
    double s = 0.0, ss = 0.0;
    for (int i = 0; i < 256; ++i) {
        const float v = Y[(size_t)(r0 + i) * NF + col];
        s  += (double)v;
        ss += (double)v * (double)v;
    }
    atomicAdd(&dsum[col], s);
    atomicAdd(&dsqs[col], ss);
}

// ---------------------------------------------------------------------------
// Kernel 4: finalize mean / rstd / boost (f64 + f32 copies)
// ---------------------------------------------------------------------------
__global__ __launch_bounds__(256) void stats_final(
    const double* __restrict__ dsum, const double* __restrict__ dsqs,
    const float* __restrict__ duty, const int* __restrict__ kp,
    double* __restrict__ mean64, double* __restrict__ rstd64, double* __restrict__ boost64,
    float* __restrict__ mean32, float* __restrict__ rstd32, float* __restrict__ boost32)
{
    const int c = blockIdx.x * 256 + threadIdx.x;
    const double m   = dsum[c] / (double)BATCH;
    const double var = dsqs[c] / (double)BATCH - m * m;
    const double rs  = 1.0 / sqrt(var + (double)BN_EPS);
    const double td  = (double)(*kp) / (double)NF;
    const double bf  = exp(td - (double)duty[c]);
    mean64[c] = m;  rstd64[c] = rs;  boost64[c] = bf;
    mean32[c] = (float)m; rstd32[c] = (float)rs; boost32[c] = (float)bf;
}

// ---------------------------------------------------------------------------
// Kernel 5: per-row BN-apply + boosted top-k (radix select, f32) with f64
// band refinement near the cutoff + scatter (in place). One block per row.
// ---------------------------------------------------------------------------
#define BAND 1e-4f
#define MAXCAND 64

__global__ __launch_bounds__(256) void topk_kernel(
    const float* __restrict__ mean32, const float* __restrict__ rstd32,
    const float* __restrict__ boost32,
    const double* __restrict__ mean64, const double* __restrict__ rstd64,
    const double* __restrict__ boost64,
    const int* __restrict__ kp,
    const float* __restrict__ X, const float* __restrict__ W,
    const int* __restrict__ Mk, const float* __restrict__ bias,
    float* __restrict__ Y)
{
    __shared__ float    yv[NF];
    __shared__ unsigned keys[NF];
    __shared__ unsigned hist[256];
    __shared__ unsigned scan[256];
    __shared__ unsigned s_bin, s_below;
    __shared__ double   red[256];
    __shared__ int      s_ncand, s_H;
    __shared__ int      cand_idx[MAXCAND];
    __shared__ double   cand_val[MAXCAND];
    __shared__ unsigned char cand_pick[MAXCAND];

    const int r = blockIdx.x;
    const int t = threadIdx.x;
    const int K = *kp;

    for (int j = 0; j < 16; ++j) {
        const int n = j * 256 + t;
        const float v   = Y[(size_t)r * NF + n];
        const float ybn = (v - mean32[n]) * rstd32[n];
        yv[n] = ybn;
        const float bst = ybn * boost32[n];
        unsigned u = __float_as_uint(bst);
        u ^= (u & 0x80000000u) ? 0xFFFFFFFFu : 0x80000000u;
        keys[n] = u;
    }
    __syncthreads();

    unsigned curval = 0u, curmask = 0u;
    int remaining = K;
    for (int pass = 3; pass >= 0; --pass) {
        const int sh = pass * 8;
        hist[t] = 0u;
        __syncthreads();
        for (int j = 0; j < 16; ++j) {
            const unsigned u = keys[j * 256 + t];
            if ((u & curmask) == curval)
                atomicAdd(&hist[(u >> sh) & 255u], 1u);
        }
        __syncthreads();
        scan[t] = hist[t];
        __syncthreads();
        for (int off = 1; off < 256; off <<= 1) {
            const unsigned add = (t + off < 256) ? scan[t + off] : 0u;
            __syncthreads();
            scan[t] += add;
            __syncthreads();
        }
        if (scan[t] >= (unsigned)remaining &&
            (t == 255 || scan[t + 1] < (unsigned)remaining)) {
            s_bin = (unsigned)t;
            s_below = (t == 255) ? 0u : scan[t + 1];
        }
        __syncthreads();
        curval |= (s_bin << sh);
        curmask |= (255u << sh);
        remaining -= (int)s_below;
        __syncthreads();
    }

    const unsigned T = curval;
    const unsigned vT = (T & 0x80000000u) ? (T ^ 0x80000000u) : ~T;
    const float cut32 = __uint_as_float(vT);
    const float cutHi = cut32 + BAND;
    const float cutLo = cut32 - BAND;

    if (t == 0) { s_ncand = 0; s_H = 0; }
    __syncthreads();
    int locH = 0;
    for (int j = 0; j < 16; ++j) {
        const int n = j * 256 + t;
        const float b = yv[n] * boost32[n];
        if (b > cutHi) {
            locH++;
        } else if (b >= cutLo) {
            const int slot = atomicAdd(&s_ncand, 1);
            if (slot < MAXCAND) cand_idx[slot] = n;
        }
    }
    atomicAdd(&s_H, locH);
    __syncthreads();
    const int H = s_H;
    const bool overflow = (s_ncand > MAXCAND);
    const int ncand = overflow ? MAXCAND : s_ncand;
    int need = K - H;
    if (need < 0) need = 0;

    if (!overflow) {
        for (int c = 0; c < ncand; ++c) {
            const int n = cand_idx[c];
            const float* xr = X + (size_t)r * INF;
            const float* wn = W + (size_t)n * INF;
            const int*   mn = Mk + (size_t)n * INF;
            double s = 0.0;
            for (int i = t; i < INF; i += 256)
                s += (double)xr[i] * (double)(wn[i] * (float)mn[i]);
            red[t] = s;
            __syncthreads();
            for (int off = 128; off > 0; off >>= 1) {
                if (t < off) red[t] += red[t + off];
                __syncthreads();
            }
            if (t == 0) {
                const double y64 = red[0] + (double)bias[n];
                cand_val[c] = (y64 - mean64[n]) * rstd64[n] * boost64[n];
                cand_pick[c] = 0;
            }
            __syncthreads();
        }
        if (t == 0) {
            for (int p = 0; p < need; ++p) {
                int best = -1;
                for (int c = 0; c < ncand; ++c) {
                    if (cand_pick[c]) continue;
                    if (best < 0 || cand_val[c] > cand_val[best] ||
                        (cand_val[c] == cand_val[best] && cand_idx[c] < cand_idx[best]))
                        best = c;
                }
                if (best < 0) break;
                cand_pick[best] = 1;
            }
        }
        __syncthreads();
        for (int j = 0; j < 16; ++j) {
            const int n = j * 256 + t;
            const float b = yv[n] * boost32[n];
            keys[n] = (b > cutHi) ? 1u : 0u;
        }
        __syncthreads();
        if (t < ncand && cand_pick[t]) keys[cand_idx[t]] = 1u;
        __syncthreads();
    } else {
        const int fneed = remaining;
        unsigned cnt = 0u;
        for (int j = 0; j < 16; ++j) cnt += (keys[t * 16 + j] == T) ? 1u : 0u;
        scan[t] = cnt;
        __syncthreads();
        for (int off = 1; off < 256; off <<= 1) {
            const unsigned add = (t >= off) ? scan[t - off] : 0u;
            __syncthreads();
            scan[t] += add;
            __syncthreads();
        }
        unsigned rank = scan[t] - cnt;
        for (int j = 0; j < 16; ++j) {
            const int n = t * 16 + j;
            const unsigned u = keys[n];
            bool sel;
            if (u == T) { sel = ((int)rank < fneed); rank++; }
            else        { sel = (u > T); }
            keys[n] = sel ? 1u : 0u;
        }
        __syncthreads();
    }

    for (int j = 0; j < 16; ++j) {
        const int n = j * 256 + t;
        Y[(size_t)r * NF + n] = keys[n] ? yv[n] : 0.0f;
    }
}

// ---------------------------------------------------------------------------
extern "C" void kernel_launch(void* const* d_in, const int* in_sizes, int n_in,
                              void* d_out, int out_size, void* d_ws, size_t ws_size,
                              hipStream_t stream)
{
    const float* x     = (const float*)d_in[0];
    const float* W     = (const float*)d_in[1];
    const float* b     = (const float*)d_in[2];
    const int*   wmask = (const int*)d_in[3];
    const float* duty  = (const float*)d_in[4];
    const int*   kp    = (const int*)d_in[5];
    float* out = (float*)d_out;

    const size_t SPLIT_X_ELTS = (size_t)3 * BATCH * INF;   // ushorts
    const size_t SPLIT_W_ELTS = (size_t)3 * NF * INF;
    const size_t STATS_BYTES  = (size_t)5 * NF * sizeof(double) + (size_t)3 * NF * sizeof(float);
    const size_t NEED_FAST    = (SPLIT_X_ELTS + SPLIT_W_ELTS) * sizeof(ushort) + STATS_BYTES;
    const bool fast = (ws_size >= NEED_FAST);

    ushort* xs  = (ushort*)d_ws;
    ushort* wsp = xs + SPLIT_X_ELTS;
    char* statbase = fast ? (char*)(wsp + SPLIT_W_ELTS) : (char*)d_ws;

    double* dsum    = (double*)statbase;     // [4096]
    double* dsqs    = dsum + NF;             // [4096]
    double* mean64  = dsqs + NF;             // [4096]
    double* rstd64  = mean64 + NF;           // [4096]
    double* boost64 = rstd64 + NF;           // [4096]
    float*  mean32  = (float*)(boost64 + NF);
    float*  rstd32  = mean32 + NF;
    float*  boost32 = rstd32 + NF;

    hipLaunchKernelGGL(zero_ws, dim3(2 * NF / 256), dim3(256), 0, stream, dsum);

    if (fast) {
        hipLaunchKernelGGL(split_x_kernel, dim3(BATCH * 128 / 256), dim3(256), 0, stream,
                           x, xs);
        hipLaunchKernelGGL(split_w_kernel, dim3(NF * 128 / 256), dim3(256), 0, stream,
                           W, wmask, wsp);
        hipFuncSetAttribute((const void*)gemm_mfma_8ph,
                            hipFuncAttributeMaxDynamicSharedMemorySize, 147456);
        hipLaunchKernelGGL(gemm_mfma_8ph, dim3(NF / 128, BATCH / 256), dim3(512), 147456,
                           stream, xs, wsp, b, out);
    } else {
        hipLaunchKernelGGL(gemm_mfma_split, dim3(NF / 128, BATCH / 128), dim3(512), 0, stream,
                           x, W, wmask, b, out);
    }

    hipLaunchKernelGGL(stats_partial, dim3(NF / 256, BATCH / 256), dim3(256), 0, stream,
                       out, dsum, dsqs);
    hipLaunchKernelGGL(stats_final, dim3(NF / 256), dim3(256), 0, stream,
                       dsum, dsqs, duty, kp,
                       mean64, rstd64, boost64, mean32, rstd32, boost32);
    hipLaunchKernelGGL(topk_kernel, dim3(BATCH), dim3(256), 0, stream,
                       mean32, rstd32, boost32, mean64, rstd64, boost64, kp,
                       x, W, wmask, b, out);
}

// Round 11
// 747.855 us; speedup vs baseline: 1.6597x; 1.6597x over previous
//
#include <hip/hip_runtime.h>

// Problem constants (fixed-shape: B=8192, IN=1024, N=4096, K=409)
#define BATCH 8192
#define INF   1024
#define NF    4096
#define BN_EPS 1e-5
#define NT    96     // K' tiles: 6 segments * 16 tiles of 64

typedef __attribute__((ext_vector_type(8))) short short8v;
typedef __attribute__((ext_vector_type(4))) float f32x4;

#define FENCE asm volatile("" ::: "memory")
#define BARRIER do { FENCE; __builtin_amdgcn_s_barrier(); FENCE; } while (0)

// ---------------------------------------------------------------------------
// Kernel 1: zero the f64 stats accumulators (2*4096 doubles)
// ---------------------------------------------------------------------------
__global__ void zero_ws(double* __restrict__ p) {
    p[blockIdx.x * 256 + threadIdx.x] = 0.0;
}

// ---------------------------------------------------------------------------
// Exact 3-way bf16 truncation split: x == bf16(h0)+bf16(h1)+bf16(h2) EXACTLY.
// ---------------------------------------------------------------------------
__device__ __forceinline__ void split3(float x, ushort& h0, ushort& h1, ushort& h2) {
    const unsigned u0 = __float_as_uint(x) & 0xFFFF0000u;
    const float    r1 = x - __uint_as_float(u0);
    const unsigned u1 = __float_as_uint(r1) & 0xFFFF0000u;
    const float    r2 = r1 - __uint_as_float(u1);
    h0 = (ushort)(u0 >> 16);
    h1 = (ushort)(u1 >> 16);
    h2 = (ushort)(__float_as_uint(r2) >> 16);
}

// ---------------------------------------------------------------------------
// Pre-split X / masked-W into 3 bf16 planes, stored PRE-SWIZZLED:
// 16B-unit j of row stored at unit (j&~7) | ((j&7) ^ (row&7)).
// global_load_lds stages linearly; swizzled ds_reads are conflict-free
// (verified R9: SQ_LDS_BANK_CONFLICT == 0).
// ---------------------------------------------------------------------------
__global__ __launch_bounds__(256) void split_x_kernel(
    const float* __restrict__ X, ushort* __restrict__ xs)
{
    const int tid = blockIdx.x * 256 + threadIdx.x;
    const int row = tid >> 7;            // 128 units per row
    const int j   = tid & 127;           // source chunk
    const size_t LS = (size_t)BATCH * INF;
    const float* src = X + (size_t)row * INF + j * 8;
    const float4 v0 = *(const float4*)(src);
    const float4 v1 = *(const float4*)(src + 4);
    const float v[8] = {v0.x, v0.y, v0.z, v0.w, v1.x, v1.y, v1.z, v1.w};
    short8v s0, s1, s2;
#pragma unroll
    for (int i = 0; i < 8; ++i) {
        ushort h0, h1, h2;
        split3(v[i], h0, h1, h2);
        s0[i] = (short)h0; s1[i] = (short)h1; s2[i] = (short)h2;
    }
    const int dj = (j & ~7) | ((j & 7) ^ (row & 7));
    const size_t du = ((size_t)row * 128 + dj) * 8;
    *(short8v*)&xs[du]          = s0;
    *(short8v*)&xs[du + LS]     = s1;
    *(short8v*)&xs[du + 2 * LS] = s2;
}

__global__ __launch_bounds__(256) void split_w_kernel(
    const float* __restrict__ W, const int* __restrict__ Mk, ushort* __restrict__ wsp)
{
    const int tid = blockIdx.x * 256 + threadIdx.x;
    const int row = tid >> 7;
    const int j   = tid & 127;
    const size_t LS = (size_t)NF * INF;
    const float* src = W + (size_t)row * INF + j * 8;
    const int*   msk = Mk + (size_t)row * INF + j * 8;
    const float4 v0 = *(const float4*)(src);
    const float4 v1 = *(const float4*)(src + 4);
    const int4   m0 = *(const int4*)(msk);
    const int4   m1 = *(const int4*)(msk + 4);
    const float v[8] = {v0.x * (float)m0.x, v0.y * (float)m0.y,
                        v0.z * (float)m0.z, v0.w * (float)m0.w,
                        v1.x * (float)m1.x, v1.y * (float)m1.y,
                        v1.z * (float)m1.z, v1.w * (float)m1.w};
    short8v s0, s1, s2;
#pragma unroll
    for (int i = 0; i < 8; ++i) {
        ushort h0, h1, h2;
        split3(v[i], h0, h1, h2);
        s0[i] = (short)h0; s1[i] = (short)h1; s2[i] = (short)h2;
    }
    const int dj = (j & ~7) | ((j & 7) ^ (row & 7));
    const size_t du = ((size_t)row * 128 + dj) * 8;
    *(short8v*)&wsp[du]          = s0;
    *(short8v*)&wsp[du + LS]     = s1;
    *(short8v*)&wsp[du + 2 * LS] = s2;
}

// ---------------------------------------------------------------------------
// direct global->LDS 16B staging
// ---------------------------------------------------------------------------
__device__ __forceinline__ void gload16(const ushort* g, ushort* l) {
    __builtin_amdgcn_global_load_lds(
        (const __attribute__((address_space(1))) void*)g,
        (__attribute__((address_space(3))) void*)l, 16, 0, 0);
}

// ---------------------------------------------------------------------------
// Kernel 2 (fast path): deep-pipelined MFMA GEMM over the 6-plane product,
// one bf16 GEMM with K' = 6144 (segments small-first:
// A[2,1,0,1,0,0] x B[0,1,2,0,1,0]).
// R11 geometry = R7's proven spill-free shape: BM=BN=128, BK=64, 512 thr =
// 8 waves (4M x 2N), 32 outputs/thread -> state = 32 f32 acc + 64 regs f64
// shadow = 96 regs (R9/R10's BM=256 had 192 -> spill; that was the bug).
// Triple-buffered LDS (96KB dynamic), tile t+2 staged via global_load_lds
// during tile t, ONE barrier per tile, counted vmcnt(4), setprio on MFMA.
// Buffers rotate via 3-unrolled loop -> all LDS offsets compile-time.
// Numerics identical to R9 (passed): f64 shadow drain every 2 tiles.
// ---------------------------------------------------------------------------
__global__ __launch_bounds__(512) void gemm_mfma_p3(
    const ushort* __restrict__ Xs, const ushort* __restrict__ Wsp,
    const float* __restrict__ bias, float* __restrict__ Y)
{
    extern __shared__ ushort sm[];   // 3 bufs x (A 8192 + B 8192 ushorts) = 96KB
    const size_t LSX = (size_t)BATCH * INF;
    const size_t LSW = (size_t)NF * INF;

    const int t    = threadIdx.x;
    const int row0 = blockIdx.y * 128;
    const int col0 = blockIdx.x * 128;

    const int l   = t & 63;
    const int l15 = l & 15;
    const int hi  = l >> 4;
    const int wid = t >> 6;
    const int wm  = wid >> 1;        // 0..3 -> M offset wm*32
    const int wn  = wid & 1;         // 0..1 -> N offset wn*64

    const int u0r = t >> 3;          // 0..63: staging row within 64-row group
    const int u0v = t & 7;           // staging k-unit

    f32x4  acc[2][4];
    double mst[2][4][4];
#pragma unroll
    for (int mf = 0; mf < 2; ++mf)
#pragma unroll
        for (int nf = 0; nf < 4; ++nf) {
            acc[mf][nf] = (f32x4){0.f, 0.f, 0.f, 0.f};
#pragma unroll
            for (int r = 0; r < 4; ++r) mst[mf][nf][r] = 0.0;
        }

#define smA(b) (sm + (b) * 16384)
#define smB(b) (sm + (b) * 16384 + 8192)

    // ---- prologue: stage tiles 0 (buf0) and 1 (buf1); segment 0 = A2 x B0 --
    {
        const ushort* Apl = Xs + 2 * LSX;
        const ushort* Bpl = Wsp;
#pragma unroll
        for (int tt = 0; tt < 2; ++tt) {
#pragma unroll
            for (int r = 0; r < 2; ++r) {
                gload16(Apl + ((size_t)(row0 + r * 64 + u0r) * 128 + tt * 8 + u0v) * 8,
                        smA(tt) + (size_t)(r * 512 + t) * 8);
                gload16(Bpl + ((size_t)(col0 + r * 64 + u0r) * 128 + tt * 8 + u0v) * 8,
                        smB(tt) + (size_t)(r * 512 + t) * 8);
            }
        }
    }
    asm volatile("s_waitcnt vmcnt(4)" ::: "memory");
    BARRIER;

    // ---- one K'-tile: stage t+2 into DST, compute from CUR, 1 barrier ----
#define TILE(tt, CUR, DST) do {                                               \
    const int t2_ = (tt) + 2;                                                 \
    if (t2_ < NT) {                                                           \
        const int s2_ = t2_ >> 4, kt2_ = t2_ & 15;                            \
        const int ap_ = (s2_ == 0) ? 2 : ((s2_ == 1 || s2_ == 3) ? 1 : 0);    \
        const int bp_ = (s2_ == 2) ? 2 : ((s2_ == 1 || s2_ == 4) ? 1 : 0);    \
        const ushort* Ap_ = Xs + (size_t)ap_ * LSX;                           \
        const ushort* Bp_ = Wsp + (size_t)bp_ * LSW;                          \
        gload16(Ap_ + ((size_t)(row0 + u0r) * 128 + kt2_ * 8 + u0v) * 8,      \
                smA(DST) + (size_t)t * 8);                                    \
        gload16(Ap_ + ((size_t)(row0 + 64 + u0r) * 128 + kt2_ * 8 + u0v) * 8, \
                smA(DST) + (size_t)(512 + t) * 8);                            \
        gload16(Bp_ + ((size_t)(col0 + u0r) * 128 + kt2_ * 8 + u0v) * 8,      \
                smB(DST) + (size_t)t * 8);                                    \
        gload16(Bp_ + ((size_t)(col0 + 64 + u0r) * 128 + kt2_ * 8 + u0v) * 8, \
                smB(DST) + (size_t)(512 + t) * 8);                            \
    }                                                                         \
    short8v Af_[2][2], Bf_[4][2];                                             \
    _Pragma("unroll")                                                         \
    for (int mf = 0; mf < 2; ++mf) {                                          \
        const int ra = wm * 32 + mf * 16 + l15;                               \
        _Pragma("unroll")                                                     \
        for (int ks = 0; ks < 2; ++ks)                                        \
            Af_[mf][ks] = *(const short8v*)&smA(CUR)[ra * 64 +                \
                              (((ks * 4 + hi) ^ (ra & 7)) << 3)];             \
    }                                                                         \
    _Pragma("unroll")                                                         \
    for (int nf = 0; nf < 4; ++nf) {                                          \
        const int rb = wn * 64 + nf * 16 + l15;                               \
        _Pragma("unroll")                                                     \
        for (int ks = 0; ks < 2; ++ks)                                        \
            Bf_[nf][ks] = *(const short8v*)&smB(CUR)[rb * 64 +                \
                              (((ks * 4 + hi) ^ (rb & 7)) << 3)];             \
    }                                                                         \
    __builtin_amdgcn_s_setprio(1);                                            \
    _Pragma("unroll")                                                         \
    for (int mf = 0; mf < 2; ++mf)                                            \
        _Pragma("unroll")                                                     \
        for (int nf = 0; nf < 4; ++nf) {                                      \
            f32x4 c = acc[mf][nf];                                            \
            c = __builtin_amdgcn_mfma_f32_16x16x32_bf16(Af_[mf][0], Bf_[nf][0], c, 0, 0, 0); \
            c = __builtin_amdgcn_mfma_f32_16x16x32_bf16(Af_[mf][1], Bf_[nf][1], c, 0, 0, 0); \
            acc[mf][nf] = c;                                                  \
        }                                                                     \
    __builtin_amdgcn_s_setprio(0);                                            \
    if ((tt) & 1) {                                                           \
        _Pragma("unroll")                                                     \
        for (int mf = 0; mf < 2; ++mf)                                        \
            _Pragma("unroll")                                                 \
            for (int nf = 0; nf < 4; ++nf) {                                  \
                _Pragma("unroll")                                             \
                for (int r = 0; r < 4; ++r)                                   \
                    mst[mf][nf][r] += (double)acc[mf][nf][r];                 \
                acc[mf][nf] = (f32x4){0.f, 0.f, 0.f, 0.f};                    \
            }                                                                 \
    }                                                                         \
    if ((tt) < NT - 2)       { asm volatile("s_waitcnt vmcnt(4)" ::: "memory"); } \
    else if ((tt) == NT - 2) { asm volatile("s_waitcnt vmcnt(0)" ::: "memory"); } \
    BARRIER;                                                                  \
} while (0)

    for (int tb = 0; tb < NT; tb += 3) {
        TILE(tb,     0, 2);
        TILE(tb + 1, 1, 0);
        TILE(tb + 2, 2, 1);
    }
#undef TILE
#undef smA
#undef smB

    // ---- epilogue: bias in f64, store f32 ----
#pragma unroll
    for (int mf = 0; mf < 2; ++mf)
#pragma unroll
        for (int nf = 0; nf < 4; ++nf) {
            const int colc = col0 + wn * 64 + nf * 16 + l15;
            const double bb = (double)bias[colc];
#pragma unroll
            for (int r = 0; r < 4; ++r) {
                const int roww = row0 + wm * 32 + mf * 16 + hi * 4 + r;
                Y[(size_t)roww * NF + colc] = (float)(mst[mf][nf][r] + bb);
            }
        }
}

// ---------------------------------------------------------------------------
// Kernel 2 (fallback, ws too small): in-kernel split, 6 products (R7 code).
// ---------------------------------------------------------------------------
__global__ __launch_bounds__(512) void gemm_mfma_split(
    const float* __restrict__ X, const float* __restrict__ W,
    const int* __restrict__ Mk, const float* __restrict__ bias,
    float* __restrict__ Y)
{
    __shared__ __align__(16) ushort a0s[128 * 40];
    __shared__ __align__(16) ushort a1s[128 * 40];
    __shared__ __align__(16) ushort a2s[128 * 40];
    __shared__ __align__(16) ushort b0s[128 * 40];
    __shared__ __align__(16) ushort b1s[128 * 40];
    __shared__ __align__(16) ushort b2s[128 * 40];

    const int t = threadIdx.x;
    const int row0 = blockIdx.y * 128;
    const int col0 = blockIdx.x * 128;
    const int srow = t >> 2;
    const int skb  = (t & 3) * 8;

    const float* Xp = X + (size_t)(row0 + srow) * INF + skb;
    const float* Wp = W + (size_t)(col0 + srow) * INF + skb;
    const int*   Mp = Mk + (size_t)(col0 + srow) * INF + skb;

    const int l   = t & 63;
    const int l15 = l & 15;
    const int hi  = l >> 4;
    const int wid = t >> 6;
    const int wm  = wid >> 1;
    const int wn  = wid & 1;

    f32x4  acc[2][4];
    double sh[2][4][4];
#pragma unroll
    for (int mf = 0; mf < 2; ++mf)
#pragma unroll
        for (int nf = 0; nf < 4; ++nf) {
            acc[mf][nf] = (f32x4){0.f, 0.f, 0.f, 0.f};
#pragma unroll
            for (int r = 0; r < 4; ++r) sh[mf][nf][r] = 0.0;
        }

    float4 xA0 = *(const float4*)(Xp);
    float4 xA1 = *(const float4*)(Xp + 4);
    float4 wB0 = *(const float4*)(Wp);
    float4 wB1 = *(const float4*)(Wp + 4);
    int4   mB0 = *(const int4*)(Mp);
    int4   mB1 = *(const int4*)(Mp + 4);

    for (int k0 = 0; k0 < INF; k0 += 32) {
        __syncthreads();
        {
            const float v[8] = {xA0.x, xA0.y, xA0.z, xA0.w, xA1.x, xA1.y, xA1.z, xA1.w};
            short8v s0, s1, s2;
#pragma unroll
            for (int i = 0; i < 8; ++i) {
                ushort h0, h1, h2;
                split3(v[i], h0, h1, h2);
                s0[i] = (short)h0; s1[i] = (short)h1; s2[i] = (short)h2;
            }
            const int off = srow * 40 + skb;
            *(short8v*)&a0s[off] = s0;
            *(short8v*)&a1s[off] = s1;
            *(short8v*)&a2s[off] = s2;
        }
        {
            const float wv[8] = {wB0.x * (float)mB0.x, wB0.y * (float)mB0.y,
                                 wB0.z * (float)mB0.z, wB0.w * (float)mB0.w,
                                 wB1.x * (float)mB1.x, wB1.y * (float)mB1.y,
                                 wB1.z * (float)mB1.z, wB1.w * (float)mB1.w};
            short8v s0, s1, s2;
#pragma unroll
            for (int i = 0; i < 8; ++i) {
                ushort h0, h1, h2;
                split3(wv[i], h0, h1, h2);
                s0[i] = (short)h0; s1[i] = (short)h1; s2[i] = (short)h2;
            }
            const int off = srow * 40 + skb;
            *(short8v*)&b0s[off] = s0;
            *(short8v*)&b1s[off] = s1;
            *(short8v*)&b2s[off] = s2;
        }
        __syncthreads();

        if (k0 + 32 < INF) {
            const int kn = k0 + 32;
            xA0 = *(const float4*)(Xp + kn);
            xA1 = *(const float4*)(Xp + kn + 4);
            wB0 = *(const float4*)(Wp + kn);
            wB1 = *(const float4*)(Wp + kn + 4);
            mB0 = *(const int4*)(Mp + kn);
            mB1 = *(const int4*)(Mp + kn + 4);
        }

        short8v A[2][3], B[4][3];
#pragma unroll
        for (int mf = 0; mf < 2; ++mf) {
            const int roff = (wm * 32 + mf * 16 + l15) * 40 + hi * 8;
            A[mf][0] = *(const short8v*)&a0s[roff];
            A[mf][1] = *(const short8v*)&a1s[roff];
            A[mf][2] = *(const short8v*)&a2s[roff];
        }
#pragma unroll
        for (int nf = 0; nf < 4; ++nf) {
            const int roff = (wn * 64 + nf * 16 + l15) * 40 + hi * 8;
            B[nf][0] = *(const short8v*)&b0s[roff];
            B[nf][1] = *(const short8v*)&b1s[roff];
            B[nf][2] = *(const short8v*)&b2s[roff];
        }

#pragma unroll
        for (int mf = 0; mf < 2; ++mf)
#pragma unroll
            for (int nf = 0; nf < 4; ++nf) {
                f32x4 c = acc[mf][nf];
                c = __builtin_amdgcn_mfma_f32_16x16x32_bf16(A[mf][0], B[nf][0], c, 0, 0, 0);
                c = __builtin_amdgcn_mfma_f32_16x16x32_bf16(A[mf][0], B[nf][1], c, 0, 0, 0);
                c = __builtin_amdgcn_mfma_f32_16x16x32_bf16(A[mf][1], B[nf][0], c, 0, 0, 0);
                c = __builtin_amdgcn_mfma_f32_16x16x32_bf16(A[mf][0], B[nf][2], c, 0, 0, 0);
                c = __builtin_amdgcn_mfma_f32_16x16x32_bf16(A[mf][1], B[nf][1], c, 0, 0, 0);
                c = __builtin_amdgcn_mfma_f32_16x16x32_bf16(A[mf][2], B[nf][0], c, 0, 0, 0);
                acc[mf][nf] = c;
            }

        if (k0 & 32) {
#pragma unroll
            for (int mf = 0; mf < 2; ++mf)
#pragma unroll
                for (int nf = 0; nf < 4; ++nf) {
#pragma unroll
                    for (int r = 0; r < 4; ++r) sh[mf][nf][r] += (double)acc[mf][nf][r];
                    acc[mf][nf] = (f32x4){0.f, 0.f, 0.f, 0.f};
                }
        }
    }

#pragma unroll
    for (int mf = 0; mf < 2; ++mf)
#pragma unroll
        for (int nf = 0; nf < 4; ++nf) {
            const int col = col0 + wn * 64 + nf * 16 + l15;
            const double bb = (double)bias[col];
#pragma unroll
            for (int r = 0; r < 4; ++r) {
                const int row = row0 + wm * 32 + mf * 16 + hi * 4 + r;
                Y[(size_t)row * NF + col] = (float)(sh[mf][nf][r] + bb);
            }
        }
}

// ---------------------------------------------------------------------------
// Kernel 3: per-column partial sums (f64) over 256-row chunks
// ---------------------------------------------------------------------------
__global__ __launch_bounds__(256) void stats_partial(
    const float* __restrict__ Y, double* __restrict__ dsum, double* __restrict__ dsqs)
{
    const int col = blockIdx.x * 256 + threadIdx.x;
    const int r0  = blockIdx.y * 256;
    double s = 0.0, ss = 0.0;
    for (int i = 0; i < 256; ++i) {
        const float v = Y[(size_t)(r0 + i) * NF + col];
        s  += (double)v;
        ss += (double)v * (double)v;
    }
    atomicAdd(&dsum[col], s);
    atomicAdd(&dsqs[col], ss);
}

// ---------------------------------------------------------------------------
// Kernel 4: finalize mean / rstd / boost (f64 + f32 copies)
// ---------------------------------------------------------------------------
__global__ __launch_bounds__(256) void stats_final(
    const double* __restrict__ dsum, const double* __restrict__ dsqs,
    const float* __restrict__ duty, const int* __restrict__ kp,
    double* __restrict__ mean64, double* __restrict__ rstd64, double* __restrict__ boost64,
    float* __restrict__ mean32, float* __restrict__ rstd32, float* __restrict__ boost32)
{
    const int c = blockIdx.x * 256 + threadIdx.x;
    const double m   = dsum[c] / (double)BATCH;
    const double var = dsqs[c] / (double)BATCH - m * m;
    const double rs  = 1.0 / sqrt(var + (double)BN_EPS);
    const double td  = (double)(*kp) / (double)NF;
    const double bf  = exp(td - (double)duty[c]);
    mean64[c] = m;  rstd64[c] = rs;  boost64[c] = bf;
    mean32[c] = (float)m; rstd32[c] = (float)rs; boost32[c] = (float)bf;
}

// ---------------------------------------------------------------------------
// Kernel 5: per-row BN-apply + boosted top-k (radix select, f32) with f64
// band refinement near the cutoff + scatter (in place). One block per row.
// ---------------------------------------------------------------------------
#define BAND 1e-4f
#define MAXCAND 64

__global__ __launch_bounds__(256) void topk_kernel(
    const float* __restrict__ mean32, const float* __restrict__ rstd32,
    const float* __restrict__ boost32,
    const double* __restrict__ mean64, const double* __restrict__ rstd64,
    const double* __restrict__ boost64,
    const int* __restrict__ kp,
    const float* __restrict__ X, const float* __restrict__ W,
    const int* __restrict__ Mk, const float* __restrict__ bias,
    float* __restrict__ Y)
{
    __shared__ float    yv[NF];
    __shared__ unsigned keys[NF];
    __shared__ unsigned hist[256];
    __shared__ unsigned scan[256];
    __shared__ unsigned s_bin, s_below;
    __shared__ double   red[256];
    __shared__ int      s_ncand, s_H;
    __shared__ int      cand_idx[MAXCAND];
    __shared__ double   cand_val[MAXCAND];
    __shared__ unsigned char cand_pick[MAXCAND];

    const int r = blockIdx.x;
    const int t = threadIdx.x;
    const int K = *kp;

    for (int j = 0; j < 16; ++j) {
        const int n = j * 256 + t;
        const float v   = Y[(size_t)r * NF + n];
        const float ybn = (v - mean32[n]) * rstd32[n];
        yv[n] = ybn;
        const float bst = ybn * boost32[n];
        unsigned u = __float_as_uint(bst);
        u ^= (u & 0x80000000u) ? 0xFFFFFFFFu : 0x80000000u;
        keys[n] = u;
    }
    __syncthreads();

    unsigned curval = 0u, curmask = 0u;
    int remaining = K;
    for (int pass = 3; pass >= 0; --pass) {
        const int sh = pass * 8;
        hist[t] = 0u;
        __syncthreads();
        for (int j = 0; j < 16; ++j) {
            const unsigned u = keys[j * 256 + t];
            if ((u & curmask) == curval)
                atomicAdd(&hist[(u >> sh) & 255u], 1u);
        }
        __syncthreads();
        scan[t] = hist[t];
        __syncthreads();
        for (int off = 1; off < 256; off <<= 1) {
            const unsigned add = (t + off < 256) ? scan[t + off] : 0u;
            __syncthreads();
            scan[t] += add;
            __syncthreads();
        }
        if (scan[t] >= (unsigned)remaining &&
            (t == 255 || scan[t + 1] < (unsigned)remaining)) {
            s_bin = (unsigned)t;
            s_below = (t == 255) ? 0u : scan[t + 1];
        }
        __syncthreads();
        curval |= (s_bin << sh);
        curmask |= (255u << sh);
        remaining -= (int)s_below;
        __syncthreads();
    }

    const unsigned T = curval;
    const unsigned vT = (T & 0x80000000u) ? (T ^ 0x80000000u) : ~T;
    const float cut32 = __uint_as_float(vT);
    const float cutHi = cut32 + BAND;
    const float cutLo = cut32 - BAND;

    if (t == 0) { s_ncand = 0; s_H = 0; }
    __syncthreads();
    int locH = 0;
    for (int j = 0; j < 16; ++j) {
        const int n = j * 256 + t;
        const float b = yv[n] * boost32[n];
        if (b > cutHi) {
            locH++;
        } else if (b >= cutLo) {
            const int slot = atomicAdd(&s_ncand, 1);
            if (slot < MAXCAND) cand_idx[slot] = n;
        }
    }
    atomicAdd(&s_H, locH);
    __syncthreads();
    const int H = s_H;
    const bool overflow = (s_ncand > MAXCAND);
    const int ncand = overflow ? MAXCAND : s_ncand;
    int need = K - H;
    if (need < 0) need = 0;

    if (!overflow) {
        for (int c = 0; c < ncand; ++c) {
            const int n = cand_idx[c];
            const float* xr = X + (size_t)r * INF;
            const float* wn = W + (size_t)n * INF;
            const int*   mn = Mk + (size_t)n * INF;
            double s = 0.0;
            for (int i = t; i < INF; i += 256)
                s += (double)xr[i] * (double)(wn[i] * (float)mn[i]);
            red[t] = s;
            __syncthreads();
            for (int off = 128; off > 0; off >>= 1) {
                if (t < off) red[t] += red[t + off];
                __syncthreads();
            }
            if (t == 0) {
                const double y64 = red[0] + (double)bias[n];
                cand_val[c] = (y64 - mean64[n]) * rstd64[n] * boost64[n];
                cand_pick[c] = 0;
            }
            __syncthreads();
        }
        if (t == 0) {
            for (int p = 0; p < need; ++p) {
                int best = -1;
                for (int c = 0; c < ncand; ++c) {
                    if (cand_pick[c]) continue;
                    if (best < 0 || cand_val[c] > cand_val[best] ||
                        (cand_val[c] == cand_val[best] && cand_idx[c] < cand_idx[best]))
                        best = c;
                }
                if (best < 0) break;
                cand_pick[best] = 1;
            }
        }
        __syncthreads();
        for (int j = 0; j < 16; ++j) {
            const int n = j * 256 + t;
            const float b = yv[n] * boost32[n];
            keys[n] = (b > cutHi) ? 1u : 0u;
        }
        __syncthreads();
        if (t < ncand && cand_pick[t]) keys[cand_idx[t]] = 1u;
        __syncthreads();
    } else {
        const int fneed = remaining;
        unsigned cnt = 0u;
        for (int j = 0; j < 16; ++j) cnt += (keys[t * 16 + j] == T) ? 1u : 0u;
        scan[t] = cnt;
        __syncthreads();
        for (int off = 1; off < 256; off <<= 1) {
            const unsigned add = (t >= off) ? scan[t - off] : 0u;
            __syncthreads();
            scan[t] += add;
            __syncthreads();
        }
        unsigned rank = scan[t] - cnt;
        for (int j = 0; j < 16; ++j) {
            const int n = t * 16 + j;
            const unsigned u = keys[n];
            bool sel;
            if (u == T) { sel = ((int)rank < fneed); rank++; }
            else        { sel = (u > T); }
            keys[n] = sel ? 1u : 0u;
        }
        __syncthreads();
    }

    for (int j = 0; j < 16; ++j) {
        const int n = j * 256 + t;
        Y[(size_t)r * NF + n] = keys[n] ? yv[n] : 0.0f;
    }
}

// ---------------------------------------------------------------------------
extern "C" void kernel_launch(void* const* d_in, const int* in_sizes, int n_in,
                              void* d_out, int out_size, void* d_ws, size_t ws_size,
                              hipStream_t stream)
{
    const float* x     = (const float*)d_in[0];
    const float* W     = (const float*)d_in[1];
    const float* b     = (const float*)d_in[2];
    const int*   wmask = (const int*)d_in[3];
    const float* duty  = (const float*)d_in[4];
    const int*   kp    = (const int*)d_in[5];
    float* out = (float*)d_out;

    const size_t SPLIT_X_ELTS = (size_t)3 * BATCH * INF;   // ushorts
    const size_t SPLIT_W_ELTS = (size_t)3 * NF * INF;
    const size_t STATS_BYTES  = (size_t)5 * NF * sizeof(double) + (size_t)3 * NF * sizeof(float);
    const size_t NEED_FAST    = (SPLIT_X_ELTS + SPLIT_W_ELTS) * sizeof(ushort) + STATS_BYTES;
    const bool fast = (ws_size >= NEED_FAST);

    ushort* xs  = (ushort*)d_ws;
    ushort* wsp = xs + SPLIT_X_ELTS;
    char* statbase = fast ? (char*)(wsp + SPLIT_W_ELTS) : (char*)d_ws;

    double* dsum    = (double*)statbase;     // [4096]
    double* dsqs    = dsum + NF;             // [4096]
    double* mean64  = dsqs + NF;             // [4096]
    double* rstd64  = mean64 + NF;           // [4096]
    double* boost64 = rstd64 + NF;           // [4096]
    float*  mean32  = (float*)(boost64 + NF);
    float*  rstd32  = mean32 + NF;
    float*  boost32 = rstd32 + NF;

    hipLaunchKernelGGL(zero_ws, dim3(2 * NF / 256), dim3(256), 0, stream, dsum);

    if (fast) {
        hipLaunchKernelGGL(split_x_kernel, dim3(BATCH * 128 / 256), dim3(256), 0, stream,
                           x, xs);
        hipLaunchKernelGGL(split_w_kernel, dim3(NF * 128 / 256), dim3(256), 0, stream,
                           W, wmask, wsp);
        hipFuncSetAttribute((const void*)gemm_mfma_p3,
                            hipFuncAttributeMaxDynamicSharedMemorySize, 98304);
        hipLaunchKernelGGL(gemm_mfma_p3, dim3(NF / 128, BATCH / 128), dim3(512), 98304,
                           stream, xs, wsp, b, out);
    } else {
        hipLaunchKernelGGL(gemm_mfma_split, dim3(NF / 128, BATCH / 128), dim3(512), 0, stream,
                           x, W, wmask, b, out);
    }

    hipLaunchKernelGGL(stats_partial, dim3(NF / 256, BATCH / 256), dim3(256), 0, stream,
                       out, dsum, dsqs);
    hipLaunchKernelGGL(stats_final, dim3(NF / 256), dim3(256), 0, stream,
                       dsum, dsqs, duty, kp,
                       mean64, rstd64, boost64, mean32, rstd32, boost32);
    hipLaunchKernelGGL(topk_kernel, dim3(BATCH), dim3(256), 0, stream,
                       mean32, rstd32, boost32, mean64, rstd64, boost64, kp,
                       x, W, wmask, b, out);
}

// Round 12
// 570.069 us; speedup vs baseline: 2.1773x; 1.3119x over previous
//
#include <hip/hip_runtime.h>

// Problem constants (fixed-shape: B=8192, IN=1024, N=4096, K=409)
#define BATCH 8192
#define INF   1024
#define NF    4096
#define BN_EPS 1e-5
#define NT    32     // K tiles of 32 (all 6 plane-products per tile)

typedef __attribute__((ext_vector_type(8))) short short8v;
typedef __attribute__((ext_vector_type(4))) float f32x4;

#define FENCE asm volatile("" ::: "memory")
#define BARRIER do { FENCE; __builtin_amdgcn_s_barrier(); FENCE; } while (0)

// ---------------------------------------------------------------------------
// Kernel 1: zero the f64 stats accumulators (2*4096 doubles)
// ---------------------------------------------------------------------------
__global__ void zero_ws(double* __restrict__ p) {
    p[blockIdx.x * 256 + threadIdx.x] = 0.0;
}

// ---------------------------------------------------------------------------
// Exact 3-way bf16 truncation split: x == bf16(h0)+bf16(h1)+bf16(h2) EXACTLY.
// ---------------------------------------------------------------------------
__device__ __forceinline__ void split3(float x, ushort& h0, ushort& h1, ushort& h2) {
    const unsigned u0 = __float_as_uint(x) & 0xFFFF0000u;
    const float    r1 = x - __uint_as_float(u0);
    const unsigned u1 = __float_as_uint(r1) & 0xFFFF0000u;
    const float    r2 = r1 - __uint_as_float(u1);
    h0 = (ushort)(u0 >> 16);
    h1 = (ushort)(u1 >> 16);
    h2 = (ushort)(__float_as_uint(r2) >> 16);
}

// ---------------------------------------------------------------------------
// Pre-split X / masked-W into 3 bf16 planes (NATURAL row-major layout;
// the LDS swizzle is applied at staging-source time, not here).
// ---------------------------------------------------------------------------
__global__ __launch_bounds__(256) void split_x_kernel(
    const float* __restrict__ X, ushort* __restrict__ xs)
{
    const size_t base = ((size_t)blockIdx.x * 256 + threadIdx.x) * 8;
    const size_t LS = (size_t)BATCH * INF;
    const float4 v0 = *(const float4*)(X + base);
    const float4 v1 = *(const float4*)(X + base + 4);
    const float v[8] = {v0.x, v0.y, v0.z, v0.w, v1.x, v1.y, v1.z, v1.w};
    short8v s0, s1, s2;
#pragma unroll
    for (int i = 0; i < 8; ++i) {
        ushort h0, h1, h2;
        split3(v[i], h0, h1, h2);
        s0[i] = (short)h0; s1[i] = (short)h1; s2[i] = (short)h2;
    }
    *(short8v*)&xs[base]          = s0;
    *(short8v*)&xs[base + LS]     = s1;
    *(short8v*)&xs[base + 2 * LS] = s2;
}

__global__ __launch_bounds__(256) void split_w_kernel(
    const float* __restrict__ W, const int* __restrict__ Mk, ushort* __restrict__ wsp)
{
    const size_t base = ((size_t)blockIdx.x * 256 + threadIdx.x) * 8;
    const size_t LS = (size_t)NF * INF;
    const float4 v0 = *(const float4*)(W + base);
    const float4 v1 = *(const float4*)(W + base + 4);
    const int4   m0 = *(const int4*)(Mk + base);
    const int4   m1 = *(const int4*)(Mk + base + 4);
    const float v[8] = {v0.x * (float)m0.x, v0.y * (float)m0.y,
                        v0.z * (float)m0.z, v0.w * (float)m0.w,
                        v1.x * (float)m1.x, v1.y * (float)m1.y,
                        v1.z * (float)m1.z, v1.w * (float)m1.w};
    short8v s0, s1, s2;
#pragma unroll
    for (int i = 0; i < 8; ++i) {
        ushort h0, h1, h2;
        split3(v[i], h0, h1, h2);
        s0[i] = (short)h0; s1[i] = (short)h1; s2[i] = (short)h2;
    }
    *(short8v*)&wsp[base]          = s0;
    *(short8v*)&wsp[base + LS]     = s1;
    *(short8v*)&wsp[base + 2 * LS] = s2;
}

// ---------------------------------------------------------------------------
// direct global->LDS 16B staging
// ---------------------------------------------------------------------------
__device__ __forceinline__ void gload16(const ushort* g, ushort* l) {
    __builtin_amdgcn_global_load_lds(
        (const __attribute__((address_space(1))) void*)g,
        (__attribute__((address_space(3))) void*)l, 16, 0, 0);
}

// ---------------------------------------------------------------------------
// Kernel 2 (fast path): R7 data formulation + R11 deep pipeline.
// Per BK=32 K-tile: stage ALL 6 plane-tiles (A0,A1,A2,B0,B1,B2; 48KB) via
// global_load_lds, read 18 fragments, compute all 48 MFMAs (6 products per
// acc, R7's exact order) -> 2.67 MFMA per LDS read (2x R11's K'=6144 view).
// BM=BN=128, 512 thr = 8 waves (4M x 2N), 32 outputs/thread (spill-free).
// Triple-buffered LDS 144KB; tile t+2 staged during tile t; counted
// vmcnt(6); one raw barrier/tile; setprio on MFMA; buffers rotate via
// unrolled-by-3 loop (compile-time offsets).
// LDS swizzle: unit' = hi ^ ((row>>1)&3), applied on the staging SOURCE
// address (ws stays natural) and on ds_read -> uniform 8 lanes/bank-quad.
// Numerics BIT-IDENTICAL to R7/R11 (passed): f64 shadow drain every 2
// tiles, f64 bias, same product order.
// ---------------------------------------------------------------------------
__global__ __launch_bounds__(512) void gemm_mfma_fuse(
    const ushort* __restrict__ Xs, const ushort* __restrict__ Wsp,
    const float* __restrict__ bias, float* __restrict__ Y)
{
    extern __shared__ ushort sm[];   // 3 bufs x 6 planes x 4096 ushorts = 144KB
    const size_t LSX = (size_t)BATCH * INF;
    const size_t LSW = (size_t)NF * INF;

    const int t    = threadIdx.x;
    const int row0 = blockIdx.y * 128;
    const int col0 = blockIdx.x * 128;

    const int l   = t & 63;
    const int l15 = l & 15;
    const int hi  = l >> 4;
    const int wid = t >> 6;
    const int wm  = wid >> 1;        // 0..3 -> M offset wm*32
    const int wn  = wid & 1;         // 0..1 -> N offset wn*64

    // staging: thread t covers tile-row (t>>2), unit-slot (t&3);
    // swizzled source unit makes linear LDS hold the swizzled layout
    const int srow  = t >> 2;                      // 0..127
    const int sunit = (t & 3) ^ ((t >> 3) & 3);    // source 16B-unit

    // ds_read swizzled unit offset (ushorts); row bases are multiples of 16
    const int uoff = (hi ^ ((l15 >> 1) & 3)) << 3;

    f32x4  acc[2][4];
    double mst[2][4][4];
#pragma unroll
    for (int mf = 0; mf < 2; ++mf)
#pragma unroll
        for (int nf = 0; nf < 4; ++nf) {
            acc[mf][nf] = (f32x4){0.f, 0.f, 0.f, 0.f};
#pragma unroll
            for (int r = 0; r < 4; ++r) mst[mf][nf][r] = 0.0;
        }

#define PB(b, p) (sm + (b) * 24576 + (p) * 4096)

    // ---- prologue: stage tiles 0 (buf0) and 1 (buf1), 6 planes each ----
#pragma unroll
    for (int tt = 0; tt < 2; ++tt) {
#pragma unroll
        for (int p = 0; p < 3; ++p)
            gload16(Xs + (size_t)p * LSX + (size_t)(row0 + srow) * INF + tt * 32 + sunit * 8,
                    PB(tt, p) + (size_t)t * 8);
#pragma unroll
        for (int p = 0; p < 3; ++p)
            gload16(Wsp + (size_t)p * LSW + (size_t)(col0 + srow) * INF + tt * 32 + sunit * 8,
                    PB(tt, 3 + p) + (size_t)t * 8);
    }
    asm volatile("s_waitcnt vmcnt(6)" ::: "memory");
    BARRIER;

    // ---- one K-tile: stage t+2 into DST, compute 48 MFMAs from CUR ----
#define TILE(tt, CUR, DST) do {                                               \
    if ((tt) + 2 < NT) {                                                      \
        const int kof_ = ((tt) + 2) * 32;                                     \
        _Pragma("unroll")                                                     \
        for (int p = 0; p < 3; ++p)                                           \
            gload16(Xs + (size_t)p * LSX + (size_t)(row0 + srow) * INF + kof_ + sunit * 8, \
                    PB(DST, p) + (size_t)t * 8);                              \
        _Pragma("unroll")                                                     \
        for (int p = 0; p < 3; ++p)                                           \
            gload16(Wsp + (size_t)p * LSW + (size_t)(col0 + srow) * INF + kof_ + sunit * 8, \
                    PB(DST, 3 + p) + (size_t)t * 8);                          \
    }                                                                         \
    short8v A_[2][3], B_[4][3];                                               \
    _Pragma("unroll")                                                         \
    for (int mf = 0; mf < 2; ++mf) {                                          \
        const int ra = (wm * 32 + mf * 16 + l15) * 32 + uoff;                 \
        _Pragma("unroll")                                                     \
        for (int p = 0; p < 3; ++p)                                           \
            A_[mf][p] = *(const short8v*)&PB(CUR, p)[ra];                     \
    }                                                                         \
    _Pragma("unroll")                                                         \
    for (int nf = 0; nf < 4; ++nf) {                                          \
        const int rb = (wn * 64 + nf * 16 + l15) * 32 + uoff;                 \
        _Pragma("unroll")                                                     \
        for (int p = 0; p < 3; ++p)                                           \
            B_[nf][p] = *(const short8v*)&PB(CUR, 3 + p)[rb];                 \
    }                                                                         \
    __builtin_amdgcn_s_setprio(1);                                            \
    _Pragma("unroll")                                                         \
    for (int mf = 0; mf < 2; ++mf)                                            \
        _Pragma("unroll")                                                     \
        for (int nf = 0; nf < 4; ++nf) {                                      \
            f32x4 c = acc[mf][nf];                                            \
            c = __builtin_amdgcn_mfma_f32_16x16x32_bf16(A_[mf][0], B_[nf][0], c, 0, 0, 0); \
            c = __builtin_amdgcn_mfma_f32_16x16x32_bf16(A_[mf][0], B_[nf][1], c, 0, 0, 0); \
            c = __builtin_amdgcn_mfma_f32_16x16x32_bf16(A_[mf][1], B_[nf][0], c, 0, 0, 0); \
            c = __builtin_amdgcn_mfma_f32_16x16x32_bf16(A_[mf][0], B_[nf][2], c, 0, 0, 0); \
            c = __builtin_amdgcn_mfma_f32_16x16x32_bf16(A_[mf][1], B_[nf][1], c, 0, 0, 0); \
            c = __builtin_amdgcn_mfma_f32_16x16x32_bf16(A_[mf][2], B_[nf][0], c, 0, 0, 0); \
            acc[mf][nf] = c;                                                  \
        }                                                                     \
    __builtin_amdgcn_s_setprio(0);                                            \
    if ((tt) & 1) {                                                           \
        _Pragma("unroll")                                                     \
        for (int mf = 0; mf < 2; ++mf)                                        \
            _Pragma("unroll")                                                 \
            for (int nf = 0; nf < 4; ++nf) {                                  \
                _Pragma("unroll")                                             \
                for (int r = 0; r < 4; ++r)                                   \
                    mst[mf][nf][r] += (double)acc[mf][nf][r];                 \
                acc[mf][nf] = (f32x4){0.f, 0.f, 0.f, 0.f};                    \
            }                                                                 \
    }                                                                         \
    if ((tt) < NT - 2)       { asm volatile("s_waitcnt vmcnt(6)" ::: "memory"); } \
    else if ((tt) == NT - 2) { asm volatile("s_waitcnt vmcnt(0)" ::: "memory"); } \
    BARRIER;                                                                  \
} while (0)

    for (int tb = 0; tb + 3 <= NT; tb += 3) {
        TILE(tb,     0, 2);
        TILE(tb + 1, 1, 0);
        TILE(tb + 2, 2, 1);
    }
    // NT = 32 = 3*10 + 2 tail tiles (30 -> buf0, 31 -> buf1)
    TILE(30, 0, 2);
    TILE(31, 1, 0);
#undef TILE
#undef PB

    // ---- epilogue: bias in f64, store f32 ----
#pragma unroll
    for (int mf = 0; mf < 2; ++mf)
#pragma unroll
        for (int nf = 0; nf < 4; ++nf) {
            const int colc = col0 + wn * 64 + nf * 16 + l15;
            const double bb = (double)bias[colc];
#pragma unroll
            for (int r = 0; r < 4; ++r) {
                const int roww = row0 + wm * 32 + mf * 16 + hi * 4 + r;
                Y[(size_t)roww * NF + colc] = (float)(mst[mf][nf][r] + bb);
            }
        }
}

// ---------------------------------------------------------------------------
// Kernel 2 (fallback, ws too small): in-kernel split, 6 products (R7 code).
// ---------------------------------------------------------------------------
__global__ __launch_bounds__(512) void gemm_mfma_split(
    const float* __restrict__ X, const float* __restrict__ W,
    const int* __restrict__ Mk, const float* __restrict__ bias,
    float* __restrict__ Y)
{
    __shared__ __align__(16) ushort a0s[128 * 40];
    __shared__ __align__(16) ushort a1s[128 * 40];
    __shared__ __align__(16) ushort a2s[128 * 40];
    __shared__ __align__(16) ushort b0s[128 * 40];
    __shared__ __align__(16) ushort b1s[128 * 40];
    __shared__ __align__(16) ushort b2s[128 * 40];

    const int t = threadIdx.x;
    const int row0 = blockIdx.y * 128;
    const int col0 = blockIdx.x * 128;
    const int srow = t >> 2;
    const int skb  = (t & 3) * 8;

    const float* Xp = X + (size_t)(row0 + srow) * INF + skb;
    const float* Wp = W + (size_t)(col0 + srow) * INF + skb;
    const int*   Mp = Mk + (size_t)(col0 + srow) * INF + skb;

    const int l   = t & 63;
    const int l15 = l & 15;
    const int hi  = l >> 4;
    const int wid = t >> 6;
    const int wm  = wid >> 1;
    const int wn  = wid & 1;

    f32x4  acc[2][4];
    double sh[2][4][4];
#pragma unroll
    for (int mf = 0; mf < 2; ++mf)
#pragma unroll
        for (int nf = 0; nf < 4; ++nf) {
            acc[mf][nf] = (f32x4){0.f, 0.f, 0.f, 0.f};
#pragma unroll
            for (int r = 0; r < 4; ++r) sh[mf][nf][r] = 0.0;
        }

    float4 xA0 = *(const float4*)(Xp);
    float4 xA1 = *(const float4*)(Xp + 4);
    float4 wB0 = *(const float4*)(Wp);
    float4 wB1 = *(const float4*)(Wp + 4);
    int4   mB0 = *(const int4*)(Mp);
    int4   mB1 = *(const int4*)(Mp + 4);

    for (int k0 = 0; k0 < INF; k0 += 32) {
        __syncthreads();
        {
            const float v[8] = {xA0.x, xA0.y, xA0.z, xA0.w, xA1.x, xA1.y, xA1.z, xA1.w};
            short8v s0, s1, s2;
#pragma unroll
            for (int i = 0; i < 8; ++i) {
                ushort h0, h1, h2;
                split3(v[i], h0, h1, h2);
                s0[i] = (short)h0; s1[i] = (short)h1; s2[i] = (short)h2;
            }
            const int off = srow * 40 + skb;
            *(short8v*)&a0s[off] = s0;
            *(short8v*)&a1s[off] = s1;
            *(short8v*)&a2s[off] = s2;
        }
        {
            const float wv[8] = {wB0.x * (float)mB0.x, wB0.y * (float)mB0.y,
                                 wB0.z * (float)mB0.z, wB0.w * (float)mB0.w,
                                 wB1.x * (float)mB1.x, wB1.y * (float)mB1.y,
                                 wB1.z * (float)mB1.z, wB1.w * (float)mB1.w};
            short8v s0, s1, s2;
#pragma unroll
            for (int i = 0; i < 8; ++i) {
                ushort h0, h1, h2;
                split3(wv[i], h0, h1, h2);
                s0[i] = (short)h0; s1[i] = (short)h1; s2[i] = (short)h2;
            }
            const int off = srow * 40 + skb;
            *(short8v*)&b0s[off] = s0;
            *(short8v*)&b1s[off] = s1;
            *(short8v*)&b2s[off] = s2;
        }
        __syncthreads();

        if (k0 + 32 < INF) {
            const int kn = k0 + 32;
            xA0 = *(const float4*)(Xp + kn);
            xA1 = *(const float4*)(Xp + kn + 4);
            wB0 = *(const float4*)(Wp + kn);
            wB1 = *(const float4*)(Wp + kn + 4);
            mB0 = *(const int4*)(Mp + kn);
            mB1 = *(const int4*)(Mp + kn + 4);
        }

        short8v A[2][3], B[4][3];
#pragma unroll
        for (int mf = 0; mf < 2; ++mf) {
            const int roff = (wm * 32 + mf * 16 + l15) * 40 + hi * 8;
            A[mf][0] = *(const short8v*)&a0s[roff];
            A[mf][1] = *(const short8v*)&a1s[roff];
            A[mf][2] = *(const short8v*)&a2s[roff];
        }
#pragma unroll
        for (int nf = 0; nf < 4; ++nf) {
            const int roff = (wn * 64 + nf * 16 + l15) * 40 + hi * 8;
            B[nf][0] = *(const short8v*)&b0s[roff];
            B[nf][1] = *(const short8v*)&b1s[roff];
            B[nf][2] = *(const short8v*)&b2s[roff];
        }

#pragma unroll
        for (int mf = 0; mf < 2; ++mf)
#pragma unroll
            for (int nf = 0; nf < 4; ++nf) {
                f32x4 c = acc[mf][nf];
                c = __builtin_amdgcn_mfma_f32_16x16x32_bf16(A[mf][0], B[nf][0], c, 0, 0, 0);
                c = __builtin_amdgcn_mfma_f32_16x16x32_bf16(A[mf][0], B[nf][1], c, 0, 0, 0);
                c = __builtin_amdgcn_mfma_f32_16x16x32_bf16(A[mf][1], B[nf][0], c, 0, 0, 0);
                c = __builtin_amdgcn_mfma_f32_16x16x32_bf16(A[mf][0], B[nf][2], c, 0, 0, 0);
                c = __builtin_amdgcn_mfma_f32_16x16x32_bf16(A[mf][1], B[nf][1], c, 0, 0, 0);
                c = __builtin_amdgcn_mfma_f32_16x16x32_bf16(A[mf][2], B[nf][0], c, 0, 0, 0);
                acc[mf][nf] = c;
            }

        if (k0 & 32) {
#pragma unroll
            for (int mf = 0; mf < 2; ++mf)
#pragma unroll
                for (int nf = 0; nf < 4; ++nf) {
#pragma unroll
                    for (int r = 0; r < 4; ++r) sh[mf][nf][r] += (double)acc[mf][nf][r];
                    acc[mf][nf] = (f32x4){0.f, 0.f, 0.f, 0.f};
                }
        }
    }

#pragma unroll
    for (int mf = 0; mf < 2; ++mf)
#pragma unroll
        for (int nf = 0; nf < 4; ++nf) {
            const int col = col0 + wn * 64 + nf * 16 + l15;
            const double bb = (double)bias[col];
#pragma unroll
            for (int r = 0; r < 4; ++r) {
                const int row = row0 + wm * 32 + mf * 16 + hi * 4 + r;
                Y[(size_t)row * NF + col] = (float)(sh[mf][nf][r] + bb);
            }
        }
}

// ---------------------------------------------------------------------------
// Kernel 3: per-column partial sums (f64) over 256-row chunks
// ---------------------------------------------------------------------------
__global__ __launch_bounds__(256) void stats_partial(
    const float* __restrict__ Y, double* __restrict__ dsum, double* __restrict__ dsqs)
{
    const int col = blockIdx.x * 256 + threadIdx.x;
    const int r0  = blockIdx.y * 256;
    double s = 0.0, ss = 0.0;
    for (int i = 0; i < 256; ++i) {
        const float v = Y[(size_t)(r0 + i) * NF + col];
        s  += (double)v;
        ss += (double)v * (double)v;
    }
    atomicAdd(&dsum[col], s);
    atomicAdd(&dsqs[col], ss);
}

// ---------------------------------------------------------------------------
// Kernel 4: finalize mean / rstd / boost (f64 + f32 copies)
// ---------------------------------------------------------------------------
__global__ __launch_bounds__(256) void stats_final(
    const double* __restrict__ dsum, const double* __restrict__ dsqs,
    const float* __restrict__ duty, const int* __restrict__ kp,
    double* __restrict__ mean64, double* __restrict__ rstd64, double* __restrict__ boost64,
    float* __restrict__ mean32, float* __restrict__ rstd32, float* __restrict__ boost32)
{
    const int c = blockIdx.x * 256 + threadIdx.x;
    const double m   = dsum[c] / (double)BATCH;
    const double var = dsqs[c] / (double)BATCH - m * m;
    const double rs  = 1.0 / sqrt(var + (double)BN_EPS);
    const double td  = (double)(*kp) / (double)NF;
    const double bf  = exp(td - (double)duty[c]);
    mean64[c] = m;  rstd64[c] = rs;  boost64[c] = bf;
    mean32[c] = (float)m; rstd32[c] = (float)rs; boost32[c] = (float)bf;
}

// ---------------------------------------------------------------------------
// Kernel 5: per-row BN-apply + boosted top-k (radix select, f32) with f64
// band refinement near the cutoff + scatter (in place). One block per row.
// ---------------------------------------------------------------------------
#define BAND 1e-4f
#define MAXCAND 64

__global__ __launch_bounds__(256) void topk_kernel(
    const float* __restrict__ mean32, const float* __restrict__ rstd32,
    const float* __restrict__ boost32,
    const double* __restrict__ mean64, const double* __restrict__ rstd64,
    const double* __restrict__ boost64,
    const int* __restrict__ kp,
    const float* __restrict__ X, const float* __restrict__ W,
    const int* __restrict__ Mk, const float* __restrict__ bias,
    float* __restrict__ Y)
{
    __shared__ float    yv[NF];
    __shared__ unsigned keys[NF];
    __shared__ unsigned hist[256];
    __shared__ unsigned scan[256];
    __shared__ unsigned s_bin, s_below;
    __shared__ double   red[256];
    __shared__ int      s_ncand, s_H;
    __shared__ int      cand_idx[MAXCAND];
    __shared__ double   cand_val[MAXCAND];
    __shared__ unsigned char cand_pick[MAXCAND];

    const int r = blockIdx.x;
    const int t = threadIdx.x;
    const int K = *kp;

    for (int j = 0; j < 16; ++j) {
        const int n = j * 256 + t;
        const float v   = Y[(size_t)r * NF + n];
        const float ybn = (v - mean32[n]) * rstd32[n];
        yv[n] = ybn;
        const float bst = ybn * boost32[n];
        unsigned u = __float_as_uint(bst);
        u ^= (u & 0x80000000u) ? 0xFFFFFFFFu : 0x80000000u;
        keys[n] = u;
    }
    __syncthreads();

    unsigned curval = 0u, curmask = 0u;
    int remaining = K;
    for (int pass = 3; pass >= 0; --pass) {
        const int sh = pass * 8;
        hist[t] = 0u;
        __syncthreads();
        for (int j = 0; j < 16; ++j) {
            const unsigned u = keys[j * 256 + t];
            if ((u & curmask) == curval)
                atomicAdd(&hist[(u >> sh) & 255u], 1u);
        }
        __syncthreads();
        scan[t] = hist[t];
        __syncthreads();
        for (int off = 1; off < 256; off <<= 1) {
            const unsigned add = (t + off < 256) ? scan[t + off] : 0u;
            __syncthreads();
            scan[t] += add;
            __syncthreads();
        }
        if (scan[t] >= (unsigned)remaining &&
            (t == 255 || scan[t + 1] < (unsigned)remaining)) {
            s_bin = (unsigned)t;
            s_below = (t == 255) ? 0u : scan[t + 1];
        }
        __syncthreads();
        curval |= (s_bin << sh);
        curmask |= (255u << sh);
        remaining -= (int)s_below;
        __syncthreads();
    }

    const unsigned T = curval;
    const unsigned vT = (T & 0x80000000u) ? (T ^ 0x80000000u) : ~T;
    const float cut32 = __uint_as_float(vT);
    const float cutHi = cut32 + BAND;
    const float cutLo = cut32 - BAND;

    if (t == 0) { s_ncand = 0; s_H = 0; }
    __syncthreads();
    int locH = 0;
    for (int j = 0; j < 16; ++j) {
        const int n = j * 256 + t;
        const float b = yv[n] * boost32[n];
        if (b > cutHi) {
            locH++;
        } else if (b >= cutLo) {
            const int slot = atomicAdd(&s_ncand, 1);
            if (slot < MAXCAND) cand_idx[slot] = n;
        }
    }
    atomicAdd(&s_H, locH);
    __syncthreads();
    const int H = s_H;
    const bool overflow = (s_ncand > MAXCAND);
    const int ncand = overflow ? MAXCAND : s_ncand;
    int need = K - H;
    if (need < 0) need = 0;

    if (!overflow) {
        for (int c = 0; c < ncand; ++c) {
            const int n = cand_idx[c];
            const float* xr = X + (size_t)r * INF;
            const float* wn = W + (size_t)n * INF;
            const int*   mn = Mk + (size_t)n * INF;
            double s = 0.0;
            for (int i = t; i < INF; i += 256)
                s += (double)xr[i] * (double)(wn[i] * (float)mn[i]);
            red[t] = s;
            __syncthreads();
            for (int off = 128; off > 0; off >>= 1) {
                if (t < off) red[t] += red[t + off];
                __syncthreads();
            }
            if (t == 0) {
                const double y64 = red[0] + (double)bias[n];
                cand_val[c] = (y64 - mean64[n]) * rstd64[n] * boost64[n];
                cand_pick[c] = 0;
            }
            __syncthreads();
        }
        if (t == 0) {
            for (int p = 0; p < need; ++p) {
                int best = -1;
                for (int c = 0; c < ncand; ++c) {
                    if (cand_pick[c]) continue;
                    if (best < 0 || cand_val[c] > cand_val[best] ||
                        (cand_val[c] == cand_val[best] && cand_idx[c] < cand_idx[best]))
                        best = c;
                }
                if (best < 0) break;
                cand_pick[best] = 1;
            }
        }
        __syncthreads();
        for (int j = 0; j < 16; ++j) {
            const int n = j * 256 + t;
            const float b = yv[n] * boost32[n];
            keys[n] = (b > cutHi) ? 1u : 0u;
        }
        __syncthreads();
        if (t < ncand && cand_pick[t]) keys[cand_idx[t]] = 1u;
        __syncthreads();
    } else {
        const int fneed = remaining;
        unsigned cnt = 0u;
        for (int j = 0; j < 16; ++j) cnt += (keys[t * 16 + j] == T) ? 1u : 0u;
        scan[t] = cnt;
        __syncthreads();
        for (int off = 1; off < 256; off <<= 1) {
            const unsigned add = (t >= off) ? scan[t - off] : 0u;
            __syncthreads();
            scan[t] += add;
            __syncthreads();
        }
        unsigned rank = scan[t] - cnt;
        for (int j = 0; j < 16; ++j) {
            const int n = t * 16 + j;
            const unsigned u = keys[n];
            bool sel;
            if (u == T) { sel = ((int)rank < fneed); rank++; }
            else        { sel = (u > T); }
            keys[n] = sel ? 1u : 0u;
        }
        __syncthreads();
    }

    for (int j = 0; j < 16; ++j) {
        const int n = j * 256 + t;
        Y[(size_t)r * NF + n] = keys[n] ? yv[n] : 0.0f;
    }
}

// ---------------------------------------------------------------------------
extern "C" void kernel_launch(void* const* d_in, const int* in_sizes, int n_in,
                              void* d_out, int out_size, void* d_ws, size_t ws_size,
                              hipStream_t stream)
{
    const float* x     = (const float*)d_in[0];
    const float* W     = (const float*)d_in[1];
    const float* b     = (const float*)d_in[2];
    const int*   wmask = (const int*)d_in[3];
    const float* duty  = (const float*)d_in[4];
    const int*   kp    = (const int*)d_in[5];
    float* out = (float*)d_out;

    const size_t SPLIT_X_ELTS = (size_t)3 * BATCH * INF;   // ushorts
    const size_t SPLIT_W_ELTS = (size_t)3 * NF * INF;
    const size_t STATS_BYTES  = (size_t)5 * NF * sizeof(double) + (size_t)3 * NF * sizeof(float);
    const size_t NEED_FAST    = (SPLIT_X_ELTS + SPLIT_W_ELTS) * sizeof(ushort) + STATS_BYTES;
    const bool fast = (ws_size >= NEED_FAST);

    ushort* xs  = (ushort*)d_ws;
    ushort* wsp = xs + SPLIT_X_ELTS;
    char* statbase = fast ? (char*)(wsp + SPLIT_W_ELTS) : (char*)d_ws;

    double* dsum    = (double*)statbase;     // [4096]
    double* dsqs    = dsum + NF;             // [4096]
    double* mean64  = dsqs + NF;             // [4096]
    double* rstd64  = mean64 + NF;           // [4096]
    double* boost64 = rstd64 + NF;           // [4096]
    float*  mean32  = (float*)(boost64 + NF);
    float*  rstd32  = mean32 + NF;
    float*  boost32 = rstd32 + NF;

    hipLaunchKernelGGL(zero_ws, dim3(2 * NF / 256), dim3(256), 0, stream, dsum);

    if (fast) {
        hipLaunchKernelGGL(split_x_kernel, dim3(BATCH * INF / 8 / 256), dim3(256), 0, stream,
                           x, xs);
        hipLaunchKernelGGL(split_w_kernel, dim3(NF * INF / 8 / 256), dim3(256), 0, stream,
                           W, wmask, wsp);
        hipFuncSetAttribute((const void*)gemm_mfma_fuse,
                            hipFuncAttributeMaxDynamicSharedMemorySize, 147456);
        hipLaunchKernelGGL(gemm_mfma_fuse, dim3(NF / 128, BATCH / 128), dim3(512), 147456,
                           stream, xs, wsp, b, out);
    } else {
        hipLaunchKernelGGL(gemm_mfma_split, dim3(NF / 128, BATCH / 128), dim3(512), 0, stream,
                           x, W, wmask, b, out);
    }

    hipLaunchKernelGGL(stats_partial, dim3(NF / 256, BATCH / 256), dim3(256), 0, stream,
                       out, dsum, dsqs);
    hipLaunchKernelGGL(stats_final, dim3(NF / 256), dim3(256), 0, stream,
                       dsum, dsqs, duty, kp,
                       mean64, rstd64, boost64, mean32, rstd32, boost32);
    hipLaunchKernelGGL(topk_kernel, dim3(BATCH), dim3(256), 0, stream,
                       mean32, rstd32, boost32, mean64, rstd64, boost64, kp,
                       x, W, wmask, b, out);
}

// Round 13
// 558.253 us; speedup vs baseline: 2.2234x; 1.0212x over previous
//
#include <hip/hip_runtime.h>

// Problem constants (fixed-shape: B=8192, IN=1024, N=4096, K=409)
#define BATCH 8192
#define INF   1024
#define NF    4096
#define BN_EPS 1e-5
#define NT    32     // K tiles of 32 (all 6 plane-products per tile)

typedef __attribute__((ext_vector_type(8))) short short8v;
typedef __attribute__((ext_vector_type(4))) float f32x4;

#define FENCE asm volatile("" ::: "memory")
#define BARRIER do { FENCE; __builtin_amdgcn_s_barrier(); FENCE; } while (0)

// ---------------------------------------------------------------------------
// Kernel 1: zero the f64 stats accumulators (2*4096 doubles)
// ---------------------------------------------------------------------------
__global__ void zero_ws(double* __restrict__ p) {
    p[blockIdx.x * 256 + threadIdx.x] = 0.0;
}

// ---------------------------------------------------------------------------
// Exact 3-way bf16 truncation split: x == bf16(h0)+bf16(h1)+bf16(h2) EXACTLY.
// ---------------------------------------------------------------------------
__device__ __forceinline__ void split3(float x, ushort& h0, ushort& h1, ushort& h2) {
    const unsigned u0 = __float_as_uint(x) & 0xFFFF0000u;
    const float    r1 = x - __uint_as_float(u0);
    const unsigned u1 = __float_as_uint(r1) & 0xFFFF0000u;
    const float    r2 = r1 - __uint_as_float(u1);
    h0 = (ushort)(u0 >> 16);
    h1 = (ushort)(u1 >> 16);
    h2 = (ushort)(__float_as_uint(r2) >> 16);
}

// ---------------------------------------------------------------------------
// Pre-split X / masked-W into 3 bf16 planes (natural row-major layout).
// ---------------------------------------------------------------------------
__global__ __launch_bounds__(256) void split_x_kernel(
    const float* __restrict__ X, ushort* __restrict__ xs)
{
    const size_t base = ((size_t)blockIdx.x * 256 + threadIdx.x) * 8;
    const size_t LS = (size_t)BATCH * INF;
    const float4 v0 = *(const float4*)(X + base);
    const float4 v1 = *(const float4*)(X + base + 4);
    const float v[8] = {v0.x, v0.y, v0.z, v0.w, v1.x, v1.y, v1.z, v1.w};
    short8v s0, s1, s2;
#pragma unroll
    for (int i = 0; i < 8; ++i) {
        ushort h0, h1, h2;
        split3(v[i], h0, h1, h2);
        s0[i] = (short)h0; s1[i] = (short)h1; s2[i] = (short)h2;
    }
    *(short8v*)&xs[base]          = s0;
    *(short8v*)&xs[base + LS]     = s1;
    *(short8v*)&xs[base + 2 * LS] = s2;
}

__global__ __launch_bounds__(256) void split_w_kernel(
    const float* __restrict__ W, const int* __restrict__ Mk, ushort* __restrict__ wsp)
{
    const size_t base = ((size_t)blockIdx.x * 256 + threadIdx.x) * 8;
    const size_t LS = (size_t)NF * INF;
    const float4 v0 = *(const float4*)(W + base);
    const float4 v1 = *(const float4*)(W + base + 4);
    const int4   m0 = *(const int4*)(Mk + base);
    const int4   m1 = *(const int4*)(Mk + base + 4);
    const float v[8] = {v0.x * (float)m0.x, v0.y * (float)m0.y,
                        v0.z * (float)m0.z, v0.w * (float)m0.w,
                        v1.x * (float)m1.x, v1.y * (float)m1.y,
                        v1.z * (float)m1.z, v1.w * (float)m1.w};
    short8v s0, s1, s2;
#pragma unroll
    for (int i = 0; i < 8; ++i) {
        ushort h0, h1, h2;
        split3(v[i], h0, h1, h2);
        s0[i] = (short)h0; s1[i] = (short)h1; s2[i] = (short)h2;
    }
    *(short8v*)&wsp[base]          = s0;
    *(short8v*)&wsp[base + LS]     = s1;
    *(short8v*)&wsp[base + 2 * LS] = s2;
}

// ---------------------------------------------------------------------------
// direct global->LDS 16B staging
// ---------------------------------------------------------------------------
__device__ __forceinline__ void gload16(const ushort* g, ushort* l) {
    __builtin_amdgcn_global_load_lds(
        (const __attribute__((address_space(1))) void*)g,
        (__attribute__((address_space(3))) void*)l, 16, 0, 0);
}

// ---------------------------------------------------------------------------
// Kernel 2 (fast path): R12's proven GEMM (376us, MfmaUtil 50%, 0 conflicts)
// + fused column-stats epilogue. Stats are summed from the ROUNDED f32
// values (byte-identical semantics to the passing stats_partial) into LDS
// f64 scratch (staging buffers reused post-barrier), then one f64 atomicAdd
// per column per block -> stats_partial kernel eliminated in fast path.
// ---------------------------------------------------------------------------
__global__ __launch_bounds__(512) void gemm_mfma_fuse(
    const ushort* __restrict__ Xs, const ushort* __restrict__ Wsp,
    const float* __restrict__ bias, float* __restrict__ Y,
    double* __restrict__ dsum, double* __restrict__ dsqs)
{
    extern __shared__ ushort sm[];   // 3 bufs x 6 planes x 4096 ushorts = 144KB
    const size_t LSX = (size_t)BATCH * INF;
    const size_t LSW = (size_t)NF * INF;

    const int t    = threadIdx.x;
    const int row0 = blockIdx.y * 128;
    const int col0 = blockIdx.x * 128;

    const int l   = t & 63;
    const int l15 = l & 15;
    const int hi  = l >> 4;
    const int wid = t >> 6;
    const int wm  = wid >> 1;        // 0..3 -> M offset wm*32
    const int wn  = wid & 1;         // 0..1 -> N offset wn*64

    const int srow  = t >> 2;                      // 0..127
    const int sunit = (t & 3) ^ ((t >> 3) & 3);    // swizzled source 16B-unit
    const int uoff = (hi ^ ((l15 >> 1) & 3)) << 3; // swizzled ds_read unit

    f32x4  acc[2][4];
    double mst[2][4][4];
#pragma unroll
    for (int mf = 0; mf < 2; ++mf)
#pragma unroll
        for (int nf = 0; nf < 4; ++nf) {
            acc[mf][nf] = (f32x4){0.f, 0.f, 0.f, 0.f};
#pragma unroll
            for (int r = 0; r < 4; ++r) mst[mf][nf][r] = 0.0;
        }

#define PB(b, p) (sm + (b) * 24576 + (p) * 4096)

    // ---- prologue: stage tiles 0 (buf0) and 1 (buf1), 6 planes each ----
#pragma unroll
    for (int tt = 0; tt < 2; ++tt) {
#pragma unroll
        for (int p = 0; p < 3; ++p)
            gload16(Xs + (size_t)p * LSX + (size_t)(row0 + srow) * INF + tt * 32 + sunit * 8,
                    PB(tt, p) + (size_t)t * 8);
#pragma unroll
        for (int p = 0; p < 3; ++p)
            gload16(Wsp + (size_t)p * LSW + (size_t)(col0 + srow) * INF + tt * 32 + sunit * 8,
                    PB(tt, 3 + p) + (size_t)t * 8);
    }
    asm volatile("s_waitcnt vmcnt(6)" ::: "memory");
    BARRIER;

#define TILE(tt, CUR, DST) do {                                               \
    if ((tt) + 2 < NT) {                                                      \
        const int kof_ = ((tt) + 2) * 32;                                     \
        _Pragma("unroll")                                                     \
        for (int p = 0; p < 3; ++p)                                           \
            gload16(Xs + (size_t)p * LSX + (size_t)(row0 + srow) * INF + kof_ + sunit * 8, \
                    PB(DST, p) + (size_t)t * 8);                              \
        _Pragma("unroll")                                                     \
        for (int p = 0; p < 3; ++p)                                           \
            gload16(Wsp + (size_t)p * LSW + (size_t)(col0 + srow) * INF + kof_ + sunit * 8, \
                    PB(DST, 3 + p) + (size_t)t * 8);                          \
    }                                                                         \
    short8v A_[2][3], B_[4][3];                                               \
    _Pragma("unroll")                                                         \
    for (int mf = 0; mf < 2; ++mf) {                                          \
        const int ra = (wm * 32 + mf * 16 + l15) * 32 + uoff;                 \
        _Pragma("unroll")                                                     \
        for (int p = 0; p < 3; ++p)                                           \
            A_[mf][p] = *(const short8v*)&PB(CUR, p)[ra];                     \
    }                                                                         \
    _Pragma("unroll")                                                         \
    for (int nf = 0; nf < 4; ++nf) {                                          \
        const int rb = (wn * 64 + nf * 16 + l15) * 32 + uoff;                 \
        _Pragma("unroll")                                                     \
        for (int p = 0; p < 3; ++p)                                           \
            B_[nf][p] = *(const short8v*)&PB(CUR, 3 + p)[rb];                 \
    }                                                                         \
    __builtin_amdgcn_s_setprio(1);                                            \
    _Pragma("unroll")                                                         \
    for (int mf = 0; mf < 2; ++mf)                                            \
        _Pragma("unroll")                                                     \
        for (int nf = 0; nf < 4; ++nf) {                                      \
            f32x4 c = acc[mf][nf];                                            \
            c = __builtin_amdgcn_mfma_f32_16x16x32_bf16(A_[mf][0], B_[nf][0], c, 0, 0, 0); \
            c = __builtin_amdgcn_mfma_f32_16x16x32_bf16(A_[mf][0], B_[nf][1], c, 0, 0, 0); \
            c = __builtin_amdgcn_mfma_f32_16x16x32_bf16(A_[mf][1], B_[nf][0], c, 0, 0, 0); \
            c = __builtin_amdgcn_mfma_f32_16x16x32_bf16(A_[mf][0], B_[nf][2], c, 0, 0, 0); \
            c = __builtin_amdgcn_mfma_f32_16x16x32_bf16(A_[mf][1], B_[nf][1], c, 0, 0, 0); \
            c = __builtin_amdgcn_mfma_f32_16x16x32_bf16(A_[mf][2], B_[nf][0], c, 0, 0, 0); \
            acc[mf][nf] = c;                                                  \
        }                                                                     \
    __builtin_amdgcn_s_setprio(0);                                            \
    if ((tt) & 1) {                                                           \
        _Pragma("unroll")                                                     \
        for (int mf = 0; mf < 2; ++mf)                                        \
            _Pragma("unroll")                                                 \
            for (int nf = 0; nf < 4; ++nf) {                                  \
                _Pragma("unroll")                                             \
                for (int r = 0; r < 4; ++r)                                   \
                    mst[mf][nf][r] += (double)acc[mf][nf][r];                 \
                acc[mf][nf] = (f32x4){0.f, 0.f, 0.f, 0.f};                    \
            }                                                                 \
    }                                                                         \
    if ((tt) < NT - 2)       { asm volatile("s_waitcnt vmcnt(6)" ::: "memory"); } \
    else if ((tt) == NT - 2) { asm volatile("s_waitcnt vmcnt(0)" ::: "memory"); } \
    BARRIER;                                                                  \
} while (0)

    for (int tb = 0; tb + 3 <= NT; tb += 3) {
        TILE(tb,     0, 2);
        TILE(tb + 1, 1, 0);
        TILE(tb + 2, 2, 1);
    }
    // NT = 32 = 3*10 + 2 tail tiles
    TILE(30, 0, 2);
    TILE(31, 1, 0);
#undef TILE
#undef PB

    // ---- epilogue: bias in f64, store f32, fused column stats ----
    // LDS reuse (all frag reads complete after the loop's final BARRIER):
    double* sdsum = (double*)sm;               // [16][128]
    double* sdsqs = sdsum + 16 * 128;          // [16][128]
    const int grp = wm * 4 + hi;               // 0..15 row-group
#pragma unroll
    for (int nf = 0; nf < 4; ++nf) {
        const int colL = wn * 64 + nf * 16 + l15;   // 0..127
        const int colc = col0 + colL;
        const double bb = (double)bias[colc];
        double s = 0.0, q = 0.0;
#pragma unroll
        for (int mf = 0; mf < 2; ++mf)
#pragma unroll
            for (int r = 0; r < 4; ++r) {
                const int roww = row0 + wm * 32 + mf * 16 + hi * 4 + r;
                const float yval = (float)(mst[mf][nf][r] + bb);
                Y[(size_t)roww * NF + colc] = yval;
                s += (double)yval;
                q += (double)yval * (double)yval;
            }
        sdsum[grp * 128 + colL] = s;
        sdsqs[grp * 128 + colL] = q;
    }
    __syncthreads();
    if (t < 128) {
        double s = 0.0;
#pragma unroll
        for (int g = 0; g < 16; ++g) s += sdsum[g * 128 + t];
        atomicAdd(&dsum[col0 + t], s);
    } else if (t < 256) {
        const int c = t - 128;
        double q = 0.0;
#pragma unroll
        for (int g = 0; g < 16; ++g) q += sdsqs[g * 128 + c];
        atomicAdd(&dsqs[col0 + c], q);
    }
}

// ---------------------------------------------------------------------------
// Kernel 2 (fallback, ws too small): in-kernel split, 6 products (R7 code).
// ---------------------------------------------------------------------------
__global__ __launch_bounds__(512) void gemm_mfma_split(
    const float* __restrict__ X, const float* __restrict__ W,
    const int* __restrict__ Mk, const float* __restrict__ bias,
    float* __restrict__ Y)
{
    __shared__ __align__(16) ushort a0s[128 * 40];
    __shared__ __align__(16) ushort a1s[128 * 40];
    __shared__ __align__(16) ushort a2s[128 * 40];
    __shared__ __align__(16) ushort b0s[128 * 40];
    __shared__ __align__(16) ushort b1s[128 * 40];
    __shared__ __align__(16) ushort b2s[128 * 40];

    const int t = threadIdx.x;
    const int row0 = blockIdx.y * 128;
    const int col0 = blockIdx.x * 128;
    const int srow = t >> 2;
    const int skb  = (t & 3) * 8;

    const float* Xp = X + (size_t)(row0 + srow) * INF + skb;
    const float* Wp = W + (size_t)(col0 + srow) * INF + skb;
    const int*   Mp = Mk + (size_t)(col0 + srow) * INF + skb;

    const int l   = t & 63;
    const int l15 = l & 15;
    const int hi  = l >> 4;
    const int wid = t >> 6;
    const int wm  = wid >> 1;
    const int wn  = wid & 1;

    f32x4  acc[2][4];
    double sh[2][4][4];
#pragma unroll
    for (int mf = 0; mf < 2; ++mf)
#pragma unroll
        for (int nf = 0; nf < 4; ++nf) {
            acc[mf][nf] = (f32x4){0.f, 0.f, 0.f, 0.f};
#pragma unroll
            for (int r = 0; r < 4; ++r) sh[mf][nf][r] = 0.0;
        }

    float4 xA0 = *(const float4*)(Xp);
    float4 xA1 = *(const float4*)(Xp + 4);
    float4 wB0 = *(const float4*)(Wp);
    float4 wB1 = *(const float4*)(Wp + 4);
    int4   mB0 = *(const int4*)(Mp);
    int4   mB1 = *(const int4*)(Mp + 4);

    for (int k0 = 0; k0 < INF; k0 += 32) {
        __syncthreads();
        {
            const float v[8] = {xA0.x, xA0.y, xA0.z, xA0.w, xA1.x, xA1.y, xA1.z, xA1.w};
            short8v s0, s1, s2;
#pragma unroll
            for (int i = 0; i < 8; ++i) {
                ushort h0, h1, h2;
                split3(v[i], h0, h1, h2);
                s0[i] = (short)h0; s1[i] = (short)h1; s2[i] = (short)h2;
            }
            const int off = srow * 40 + skb;
            *(short8v*)&a0s[off] = s0;
            *(short8v*)&a1s[off] = s1;
            *(short8v*)&a2s[off] = s2;
        }
        {
            const float wv[8] = {wB0.x * (float)mB0.x, wB0.y * (float)mB0.y,
                                 wB0.z * (float)mB0.z, wB0.w * (float)mB0.w,
                                 wB1.x * (float)mB1.x, wB1.y * (float)mB1.y,
                                 wB1.z * (float)mB1.z, wB1.w * (float)mB1.w};
            short8v s0, s1, s2;
#pragma unroll
            for (int i = 0; i < 8; ++i) {
                ushort h0, h1, h2;
                split3(wv[i], h0, h1, h2);
                s0[i] = (short)h0; s1[i] = (short)h1; s2[i] = (short)h2;
            }
            const int off = srow * 40 + skb;
            *(short8v*)&b0s[off] = s0;
            *(short8v*)&b1s[off] = s1;
            *(short8v*)&b2s[off] = s2;
        }
        __syncthreads();

        if (k0 + 32 < INF) {
            const int kn = k0 + 32;
            xA0 = *(const float4*)(Xp + kn);
            xA1 = *(const float4*)(Xp + kn + 4);
            wB0 = *(const float4*)(Wp + kn);
            wB1 = *(const float4*)(Wp + kn + 4);
            mB0 = *(const int4*)(Mp + kn);
            mB1 = *(const int4*)(Mp + kn + 4);
        }

        short8v A[2][3], B[4][3];
#pragma unroll
        for (int mf = 0; mf < 2; ++mf) {
            const int roff = (wm * 32 + mf * 16 + l15) * 40 + hi * 8;
            A[mf][0] = *(const short8v*)&a0s[roff];
            A[mf][1] = *(const short8v*)&a1s[roff];
            A[mf][2] = *(const short8v*)&a2s[roff];
        }
#pragma unroll
        for (int nf = 0; nf < 4; ++nf) {
            const int roff = (wn * 64 + nf * 16 + l15) * 40 + hi * 8;
            B[nf][0] = *(const short8v*)&b0s[roff];
            B[nf][1] = *(const short8v*)&b1s[roff];
            B[nf][2] = *(const short8v*)&b2s[roff];
        }

#pragma unroll
        for (int mf = 0; mf < 2; ++mf)
#pragma unroll
            for (int nf = 0; nf < 4; ++nf) {
                f32x4 c = acc[mf][nf];
                c = __builtin_amdgcn_mfma_f32_16x16x32_bf16(A[mf][0], B[nf][0], c, 0, 0, 0);
                c = __builtin_amdgcn_mfma_f32_16x16x32_bf16(A[mf][0], B[nf][1], c, 0, 0, 0);
                c = __builtin_amdgcn_mfma_f32_16x16x32_bf16(A[mf][1], B[nf][0], c, 0, 0, 0);
                c = __builtin_amdgcn_mfma_f32_16x16x32_bf16(A[mf][0], B[nf][2], c, 0, 0, 0);
                c = __builtin_amdgcn_mfma_f32_16x16x32_bf16(A[mf][1], B[nf][1], c, 0, 0, 0);
                c = __builtin_amdgcn_mfma_f32_16x16x32_bf16(A[mf][2], B[nf][0], c, 0, 0, 0);
                acc[mf][nf] = c;
            }

        if (k0 & 32) {
#pragma unroll
            for (int mf = 0; mf < 2; ++mf)
#pragma unroll
                for (int nf = 0; nf < 4; ++nf) {
#pragma unroll
                    for (int r = 0; r < 4; ++r) sh[mf][nf][r] += (double)acc[mf][nf][r];
                    acc[mf][nf] = (f32x4){0.f, 0.f, 0.f, 0.f};
                }
        }
    }

#pragma unroll
    for (int mf = 0; mf < 2; ++mf)
#pragma unroll
        for (int nf = 0; nf < 4; ++nf) {
            const int col = col0 + wn * 64 + nf * 16 + l15;
            const double bb = (double)bias[col];
#pragma unroll
            for (int r = 0; r < 4; ++r) {
                const int row = row0 + wm * 32 + mf * 16 + hi * 4 + r;
                Y[(size_t)row * NF + col] = (float)(sh[mf][nf][r] + bb);
            }
        }
}

// ---------------------------------------------------------------------------
// Kernel 3 (fallback path only): per-column partial sums (f64)
// ---------------------------------------------------------------------------
__global__ __launch_bounds__(256) void stats_partial(
    const float* __restrict__ Y, double* __restrict__ dsum, double* __restrict__ dsqs)
{
    const int col = blockIdx.x * 256 + threadIdx.x;
    const int r0  = blockIdx.y * 256;
    double s = 0.0, ss = 0.0;
    for (int i = 0; i < 256; ++i) {
        const float v = Y[(size_t)(r0 + i) * NF + col];
        s  += (double)v;
        ss += (double)v * (double)v;
    }
    atomicAdd(&dsum[col], s);
    atomicAdd(&dsqs[col], ss);
}

// ---------------------------------------------------------------------------
// Kernel 4: finalize mean / rstd / boost (f64 + f32 copies)
// ---------------------------------------------------------------------------
__global__ __launch_bounds__(256) void stats_final(
    const double* __restrict__ dsum, const double* __restrict__ dsqs,
    const float* __restrict__ duty, const int* __restrict__ kp,
    double* __restrict__ mean64, double* __restrict__ rstd64, double* __restrict__ boost64,
    float* __restrict__ mean32, float* __restrict__ rstd32, float* __restrict__ boost32)
{
    const int c = blockIdx.x * 256 + threadIdx.x;
    const double m   = dsum[c] / (double)BATCH;
    const double var = dsqs[c] / (double)BATCH - m * m;
    const double rs  = 1.0 / sqrt(var + (double)BN_EPS);
    const double td  = (double)(*kp) / (double)NF;
    const double bf  = exp(td - (double)duty[c]);
    mean64[c] = m;  rstd64[c] = rs;  boost64[c] = bf;
    mean32[c] = (float)m; rstd32[c] = (float)rs; boost32[c] = (float)bf;
}

// ---------------------------------------------------------------------------
// Kernel 5 (v2): per-row BN-apply + boosted top-k + f64 band refinement.
// Changes vs R12 (selection result identical):
//  - float4-vectorized load/BN/key build and final write.
//  - radix pass 1 full; boundary-bin keys COMPACTED (cap 512; full-scan
//    fallback) so passes 2-4 hist over <=512 elements instead of 4096.
//  - 256-bin suffix scans via wave shfl (2 barriers) instead of 16.
// ---------------------------------------------------------------------------
#define BAND 1e-4f
#define MAXCAND 64
#define LCAP 512

__global__ __launch_bounds__(256) void topk_kernel(
    const float* __restrict__ mean32, const float* __restrict__ rstd32,
    const float* __restrict__ boost32,
    const double* __restrict__ mean64, const double* __restrict__ rstd64,
    const double* __restrict__ boost64,
    const int* __restrict__ kp,
    const float* __restrict__ X, const float* __restrict__ W,
    const int* __restrict__ Mk, const float* __restrict__ bias,
    float* __restrict__ Y)
{
    __shared__ float    yv[NF];
    __shared__ unsigned keys[NF];
    __shared__ unsigned hist[256];
    __shared__ unsigned scan[256];
    __shared__ unsigned wtot[4];
    __shared__ unsigned s_bin, s_below;
    __shared__ int      s_cnt;
    __shared__ unsigned lkey[LCAP];
    __shared__ double   red[256];
    __shared__ int      s_ncand, s_H;
    __shared__ int      cand_idx[MAXCAND];
    __shared__ double   cand_val[MAXCAND];
    __shared__ unsigned char cand_pick[MAXCAND];

    const int r = blockIdx.x;
    const int t = threadIdx.x;
    const int K = *kp;
    const int lane = t & 63;
    const int w    = t >> 6;

    // ---- load row, BN, keys (float4 vectorized) ----
    for (int j = 0; j < 4; ++j) {
        const int n = j * 1024 + t * 4;
        const float4 v  = *(const float4*)&Y[(size_t)r * NF + n];
        const float4 mm = *(const float4*)&mean32[n];
        const float4 rs = *(const float4*)&rstd32[n];
        const float4 bo = *(const float4*)&boost32[n];
        const float yb[4] = {(v.x - mm.x) * rs.x, (v.y - mm.y) * rs.y,
                             (v.z - mm.z) * rs.z, (v.w - mm.w) * rs.w};
        const float bsv[4] = {yb[0] * bo.x, yb[1] * bo.y, yb[2] * bo.z, yb[3] * bo.w};
#pragma unroll
        for (int q = 0; q < 4; ++q) {
            yv[n + q] = yb[q];
            unsigned u = __float_as_uint(bsv[q]);
            u ^= (u & 0x80000000u) ? 0xFFFFFFFFu : 0x80000000u;
            keys[n + q] = u;
        }
    }
    __syncthreads();

    // wave-based suffix scan of hist -> scan (ends with barrier)
#define SUFFIX_SCAN() do {                                                    \
    unsigned v_ = hist[t];                                                    \
    _Pragma("unroll")                                                         \
    for (int off_ = 1; off_ < 64; off_ <<= 1) {                               \
        const unsigned o_ = __shfl_down(v_, off_, 64);                        \
        if (lane + off_ < 64) v_ += o_;                                       \
    }                                                                         \
    if (lane == 0) wtot[w] = v_;                                              \
    __syncthreads();                                                          \
    unsigned add_ = 0;                                                        \
    for (int ww_ = w + 1; ww_ < 4; ++ww_) add_ += wtot[ww_];                  \
    scan[t] = v_ + add_;                                                      \
    __syncthreads();                                                          \
} while (0)

    // ---- pass 1: full hist over top byte ----
    hist[t] = 0u;
    __syncthreads();
    for (int j = 0; j < 16; ++j)
        atomicAdd(&hist[keys[j * 256 + t] >> 24], 1u);
    __syncthreads();
    SUFFIX_SCAN();
    int remaining = K;
    if (scan[t] >= (unsigned)remaining &&
        (t == 255 || scan[t + 1] < (unsigned)remaining)) {
        s_bin = (unsigned)t;
        s_below = (t == 255) ? 0u : scan[t + 1];
    }
    if (t == 0) s_cnt = 0;
    __syncthreads();
    const unsigned b1 = s_bin;
    unsigned curval = b1 << 24;
    unsigned curmask = 0xFF000000u;
    remaining -= (int)s_below;
    __syncthreads();

    // ---- compact boundary-bin keys ----
    for (int j = 0; j < 16; ++j) {
        const unsigned u = keys[j * 256 + t];
        if ((u >> 24) == b1) {
            const int slot = atomicAdd(&s_cnt, 1);
            if (slot < LCAP) lkey[slot] = u;
        }
    }
    __syncthreads();
    const bool smallbin = (s_cnt <= LCAP);
    const int cnt = s_cnt;

    // ---- passes 2..4 (over compacted list when possible) ----
    for (int pass = 2; pass >= 0; --pass) {
        const int sh = pass * 8;
        hist[t] = 0u;
        __syncthreads();
        if (smallbin) {
            for (int i = t; i < cnt; i += 256) {
                const unsigned u = lkey[i];
                if ((u & curmask) == curval)
                    atomicAdd(&hist[(u >> sh) & 255u], 1u);
            }
        } else {
            for (int j = 0; j < 16; ++j) {
                const unsigned u = keys[j * 256 + t];
                if ((u & curmask) == curval)
                    atomicAdd(&hist[(u >> sh) & 255u], 1u);
            }
        }
        __syncthreads();
        SUFFIX_SCAN();
        if (scan[t] >= (unsigned)remaining &&
            (t == 255 || scan[t + 1] < (unsigned)remaining)) {
            s_bin = (unsigned)t;
            s_below = (t == 255) ? 0u : scan[t + 1];
        }
        __syncthreads();
        curval |= (s_bin << sh);
        curmask |= (255u << sh);
        remaining -= (int)s_below;
        __syncthreads();
    }
#undef SUFFIX_SCAN

    const unsigned T = curval;
    const unsigned vT = (T & 0x80000000u) ? (T ^ 0x80000000u) : ~T;
    const float cut32 = __uint_as_float(vT);
    const float cutHi = cut32 + BAND;
    const float cutLo = cut32 - BAND;

    // ---- classify: count definite-selects, collect band candidates ----
    if (t == 0) { s_ncand = 0; s_H = 0; }
    __syncthreads();
    int locH = 0;
    for (int j = 0; j < 16; ++j) {
        const int n = j * 256 + t;
        const float b = yv[n] * boost32[n];
        if (b > cutHi) {
            locH++;
        } else if (b >= cutLo) {
            const int slot = atomicAdd(&s_ncand, 1);
            if (slot < MAXCAND) cand_idx[slot] = n;
        }
    }
    atomicAdd(&s_H, locH);
    __syncthreads();
    const int H = s_H;
    const bool overflow = (s_ncand > MAXCAND);
    const int ncand = overflow ? MAXCAND : s_ncand;
    int need = K - H;
    if (need < 0) need = 0;

    if (!overflow) {
        // f64 band refinement: exact recompute of candidates
        for (int c = 0; c < ncand; ++c) {
            const int n = cand_idx[c];
            const float* xr = X + (size_t)r * INF;
            const float* wn = W + (size_t)n * INF;
            const int*   mn = Mk + (size_t)n * INF;
            double s = 0.0;
            for (int i = t; i < INF; i += 256)
                s += (double)xr[i] * (double)(wn[i] * (float)mn[i]);
            red[t] = s;
            __syncthreads();
            for (int off = 128; off > 0; off >>= 1) {
                if (t < off) red[t] += red[t + off];
                __syncthreads();
            }
            if (t == 0) {
                const double y64 = red[0] + (double)bias[n];
                cand_val[c] = (y64 - mean64[n]) * rstd64[n] * boost64[n];
                cand_pick[c] = 0;
            }
            __syncthreads();
        }
        if (t == 0) {
            for (int p = 0; p < need; ++p) {
                int best = -1;
                for (int c = 0; c < ncand; ++c) {
                    if (cand_pick[c]) continue;
                    if (best < 0 || cand_val[c] > cand_val[best] ||
                        (cand_val[c] == cand_val[best] && cand_idx[c] < cand_idx[best]))
                        best = c;
                }
                if (best < 0) break;
                cand_pick[best] = 1;
            }
        }
        __syncthreads();
        for (int j = 0; j < 16; ++j) {
            const int n = j * 256 + t;
            const float b = yv[n] * boost32[n];
            keys[n] = (b > cutHi) ? 1u : 0u;
        }
        __syncthreads();
        if (t < ncand && cand_pick[t]) keys[cand_idx[t]] = 1u;
        __syncthreads();
    } else {
        // fallback: pure f32 stable selection (lowest-index ties at T)
        const int fneed = remaining;
        unsigned cntk = 0u;
        for (int j = 0; j < 16; ++j) cntk += (keys[t * 16 + j] == T) ? 1u : 0u;
        scan[t] = cntk;
        __syncthreads();
        for (int off = 1; off < 256; off <<= 1) {
            const unsigned add = (t >= off) ? scan[t - off] : 0u;
            __syncthreads();
            scan[t] += add;
            __syncthreads();
        }
        unsigned rank = scan[t] - cntk;
        for (int j = 0; j < 16; ++j) {
            const int n = t * 16 + j;
            const unsigned u = keys[n];
            bool sel;
            if (u == T) { sel = ((int)rank < fneed); rank++; }
            else        { sel = (u > T); }
            keys[n] = sel ? 1u : 0u;
        }
        __syncthreads();
    }

    // ---- vectorized in-place write ----
    for (int j = 0; j < 4; ++j) {
        const int n = j * 1024 + t * 4;
        float4 o;
        o.x = keys[n + 0] ? yv[n + 0] : 0.0f;
        o.y = keys[n + 1] ? yv[n + 1] : 0.0f;
        o.z = keys[n + 2] ? yv[n + 2] : 0.0f;
        o.w = keys[n + 3] ? yv[n + 3] : 0.0f;
        *(float4*)&Y[(size_t)r * NF + n] = o;
    }
}

// ---------------------------------------------------------------------------
extern "C" void kernel_launch(void* const* d_in, const int* in_sizes, int n_in,
                              void* d_out, int out_size, void* d_ws, size_t ws_size,
                              hipStream_t stream)
{
    const float* x     = (const float*)d_in[0];
    const float* W     = (const float*)d_in[1];
    const float* b     = (const float*)d_in[2];
    const int*   wmask = (const int*)d_in[3];
    const float* duty  = (const float*)d_in[4];
    const int*   kp    = (const int*)d_in[5];
    float* out = (float*)d_out;

    const size_t SPLIT_X_ELTS = (size_t)3 * BATCH * INF;   // ushorts
    const size_t SPLIT_W_ELTS = (size_t)3 * NF * INF;
    const size_t STATS_BYTES  = (size_t)5 * NF * sizeof(double) + (size_t)3 * NF * sizeof(float);
    const size_t NEED_FAST    = (SPLIT_X_ELTS + SPLIT_W_ELTS) * sizeof(ushort) + STATS_BYTES;
    const bool fast = (ws_size >= NEED_FAST);

    ushort* xs  = (ushort*)d_ws;
    ushort* wsp = xs + SPLIT_X_ELTS;
    char* statbase = fast ? (char*)(wsp + SPLIT_W_ELTS) : (char*)d_ws;

    double* dsum    = (double*)statbase;     // [4096]
    double* dsqs    = dsum + NF;             // [4096]
    double* mean64  = dsqs + NF;             // [4096]
    double* rstd64  = mean64 + NF;           // [4096]
    double* boost64 = rstd64 + NF;           // [4096]
    float*  mean32  = (float*)(boost64 + NF);
    float*  rstd32  = mean32 + NF;
    float*  boost32 = rstd32 + NF;

    hipLaunchKernelGGL(zero_ws, dim3(2 * NF / 256), dim3(256), 0, stream, dsum);

    if (fast) {
        hipLaunchKernelGGL(split_x_kernel, dim3(BATCH * INF / 8 / 256), dim3(256), 0, stream,
                           x, xs);
        hipLaunchKernelGGL(split_w_kernel, dim3(NF * INF / 8 / 256), dim3(256), 0, stream,
                           W, wmask, wsp);
        hipFuncSetAttribute((const void*)gemm_mfma_fuse,
                            hipFuncAttributeMaxDynamicSharedMemorySize, 147456);
        hipLaunchKernelGGL(gemm_mfma_fuse, dim3(NF / 128, BATCH / 128), dim3(512), 147456,
                           stream, xs, wsp, b, out, dsum, dsqs);
    } else {
        hipLaunchKernelGGL(gemm_mfma_split, dim3(NF / 128, BATCH / 128), dim3(512), 0, stream,
                           x, W, wmask, b, out);
        hipLaunchKernelGGL(stats_partial, dim3(NF / 256, BATCH / 256), dim3(256), 0, stream,
                           out, dsum, dsqs);
    }

    hipLaunchKernelGGL(stats_final, dim3(NF / 256), dim3(256), 0, stream,
                       dsum, dsqs, duty, kp,
                       mean64, rstd64, boost64, mean32, rstd32, boost32);
    hipLaunchKernelGGL(topk_kernel, dim3(BATCH), dim3(256), 0, stream,
                       mean32, rstd32, boost32, mean64, rstd64, boost64, kp,
                       x, W, wmask, b, out);
}

// Round 14
// 547.991 us; speedup vs baseline: 2.2651x; 1.0187x over previous
//
#include <hip/hip_runtime.h>

// Problem constants (fixed-shape: B=8192, IN=1024, N=4096, K=409)
#define BATCH 8192
#define INF   1024
#define NF    4096
#define BN_EPS 1e-5
#define NT    32     // K tiles of 32 (all 6 plane-products per tile)

typedef __attribute__((ext_vector_type(8))) short short8v;
typedef __attribute__((ext_vector_type(4))) float f32x4;

#define FENCE asm volatile("" ::: "memory")
#define BARRIER do { FENCE; __builtin_amdgcn_s_barrier(); FENCE; } while (0)

// ---------------------------------------------------------------------------
// Exact 3-way bf16 truncation split: x == bf16(h0)+bf16(h1)+bf16(h2) EXACTLY.
// ---------------------------------------------------------------------------
__device__ __forceinline__ void split3(float x, ushort& h0, ushort& h1, ushort& h2) {
    const unsigned u0 = __float_as_uint(x) & 0xFFFF0000u;
    const float    r1 = x - __uint_as_float(u0);
    const unsigned u1 = __float_as_uint(r1) & 0xFFFF0000u;
    const float    r2 = r1 - __uint_as_float(u1);
    h0 = (ushort)(u0 >> 16);
    h1 = (ushort)(u1 >> 16);
    h2 = (ushort)(__float_as_uint(r2) >> 16);
}

// ---------------------------------------------------------------------------
// Kernel 1 (fast path): merged prep — zero stats (block 0) + pre-split X
// (blocks [0,4096)) and masked W (blocks [4096,6144)) into 3 bf16 planes.
// ---------------------------------------------------------------------------
__global__ __launch_bounds__(256) void prep_kernel(
    const float* __restrict__ X, const float* __restrict__ W,
    const int* __restrict__ Mk,
    ushort* __restrict__ xs, ushort* __restrict__ wsp,
    double* __restrict__ dz)
{
    const int blk = blockIdx.x;
    const int t   = threadIdx.x;
    if (blk == 0) {
#pragma unroll
        for (int i = 0; i < 32; ++i) dz[i * 256 + t] = 0.0;   // 2*NF doubles
    }
    if (blk < 4096) {
        const size_t base = ((size_t)blk * 256 + t) * 8;
        const size_t LS = (size_t)BATCH * INF;
        const float4 v0 = *(const float4*)(X + base);
        const float4 v1 = *(const float4*)(X + base + 4);
        const float v[8] = {v0.x, v0.y, v0.z, v0.w, v1.x, v1.y, v1.z, v1.w};
        short8v s0, s1, s2;
#pragma unroll
        for (int i = 0; i < 8; ++i) {
            ushort h0, h1, h2;
            split3(v[i], h0, h1, h2);
            s0[i] = (short)h0; s1[i] = (short)h1; s2[i] = (short)h2;
        }
        *(short8v*)&xs[base]          = s0;
        *(short8v*)&xs[base + LS]     = s1;
        *(short8v*)&xs[base + 2 * LS] = s2;
    } else {
        const size_t base = ((size_t)(blk - 4096) * 256 + t) * 8;
        const size_t LS = (size_t)NF * INF;
        const float4 v0 = *(const float4*)(W + base);
        const float4 v1 = *(const float4*)(W + base + 4);
        const int4   m0 = *(const int4*)(Mk + base);
        const int4   m1 = *(const int4*)(Mk + base + 4);
        const float v[8] = {v0.x * (float)m0.x, v0.y * (float)m0.y,
                            v0.z * (float)m0.z, v0.w * (float)m0.w,
                            v1.x * (float)m1.x, v1.y * (float)m1.y,
                            v1.z * (float)m1.z, v1.w * (float)m1.w};
        short8v s0, s1, s2;
#pragma unroll
        for (int i = 0; i < 8; ++i) {
            ushort h0, h1, h2;
            split3(v[i], h0, h1, h2);
            s0[i] = (short)h0; s1[i] = (short)h1; s2[i] = (short)h2;
        }
        *(short8v*)&wsp[base]          = s0;
        *(short8v*)&wsp[base + LS]     = s1;
        *(short8v*)&wsp[base + 2 * LS] = s2;
    }
}

// ---------------------------------------------------------------------------
// Kernel 1 (fallback): zero the f64 stats accumulators
// ---------------------------------------------------------------------------
__global__ void zero_ws(double* __restrict__ p) {
    p[blockIdx.x * 256 + threadIdx.x] = 0.0;
}

// ---------------------------------------------------------------------------
// direct global->LDS 16B staging
// ---------------------------------------------------------------------------
__device__ __forceinline__ void gload16(const ushort* g, ushort* l) {
    __builtin_amdgcn_global_load_lds(
        (const __attribute__((address_space(1))) void*)g,
        (__attribute__((address_space(3))) void*)l, 16, 0, 0);
}

// ---------------------------------------------------------------------------
// Kernel 2 (fast path): R12/R13's proven GEMM (MfmaUtil ~50%, 0 conflicts)
// + fused column-stats epilogue (stats from ROUNDED f32 values; 1 f64
// atomicAdd per column per block). FROZEN this round.
// ---------------------------------------------------------------------------
__global__ __launch_bounds__(512) void gemm_mfma_fuse(
    const ushort* __restrict__ Xs, const ushort* __restrict__ Wsp,
    const float* __restrict__ bias, float* __restrict__ Y,
    double* __restrict__ dsum, double* __restrict__ dsqs)
{
    extern __shared__ ushort sm[];   // 3 bufs x 6 planes x 4096 ushorts = 144KB
    const size_t LSX = (size_t)BATCH * INF;
    const size_t LSW = (size_t)NF * INF;

    const int t    = threadIdx.x;
    const int row0 = blockIdx.y * 128;
    const int col0 = blockIdx.x * 128;

    const int l   = t & 63;
    const int l15 = l & 15;
    const int hi  = l >> 4;
    const int wid = t >> 6;
    const int wm  = wid >> 1;        // 0..3 -> M offset wm*32
    const int wn  = wid & 1;         // 0..1 -> N offset wn*64

    const int srow  = t >> 2;                      // 0..127
    const int sunit = (t & 3) ^ ((t >> 3) & 3);    // swizzled source 16B-unit
    const int uoff = (hi ^ ((l15 >> 1) & 3)) << 3; // swizzled ds_read unit

    f32x4  acc[2][4];
    double mst[2][4][4];
#pragma unroll
    for (int mf = 0; mf < 2; ++mf)
#pragma unroll
        for (int nf = 0; nf < 4; ++nf) {
            acc[mf][nf] = (f32x4){0.f, 0.f, 0.f, 0.f};
#pragma unroll
            for (int r = 0; r < 4; ++r) mst[mf][nf][r] = 0.0;
        }

#define PB(b, p) (sm + (b) * 24576 + (p) * 4096)

#pragma unroll
    for (int tt = 0; tt < 2; ++tt) {
#pragma unroll
        for (int p = 0; p < 3; ++p)
            gload16(Xs + (size_t)p * LSX + (size_t)(row0 + srow) * INF + tt * 32 + sunit * 8,
                    PB(tt, p) + (size_t)t * 8);
#pragma unroll
        for (int p = 0; p < 3; ++p)
            gload16(Wsp + (size_t)p * LSW + (size_t)(col0 + srow) * INF + tt * 32 + sunit * 8,
                    PB(tt, 3 + p) + (size_t)t * 8);
    }
    asm volatile("s_waitcnt vmcnt(6)" ::: "memory");
    BARRIER;

#define TILE(tt, CUR, DST) do {                                               \
    if ((tt) + 2 < NT) {                                                      \
        const int kof_ = ((tt) + 2) * 32;                                     \
        _Pragma("unroll")                                                     \
        for (int p = 0; p < 3; ++p)                                           \
            gload16(Xs + (size_t)p * LSX + (size_t)(row0 + srow) * INF + kof_ + sunit * 8, \
                    PB(DST, p) + (size_t)t * 8);                              \
        _Pragma("unroll")                                                     \
        for (int p = 0; p < 3; ++p)                                           \
            gload16(Wsp + (size_t)p * LSW + (size_t)(col0 + srow) * INF + kof_ + sunit * 8, \
                    PB(DST, 3 + p) + (size_t)t * 8);                          \
    }                                                                         \
    short8v A_[2][3], B_[4][3];                                               \
    _Pragma("unroll")                                                         \
    for (int mf = 0; mf < 2; ++mf) {                                          \
        const int ra = (wm * 32 + mf * 16 + l15) * 32 + uoff;                 \
        _Pragma("unroll")                                                     \
        for (int p = 0; p < 3; ++p)                                           \
            A_[mf][p] = *(const short8v*)&PB(CUR, p)[ra];                     \
    }                                                                         \
    _Pragma("unroll")                                                         \
    for (int nf = 0; nf < 4; ++nf) {                                          \
        const int rb = (wn * 64 + nf * 16 + l15) * 32 + uoff;                 \
        _Pragma("unroll")                                                     \
        for (int p = 0; p < 3; ++p)                                           \
            B_[nf][p] = *(const short8v*)&PB(CUR, 3 + p)[rb];                 \
    }                                                                         \
    __builtin_amdgcn_s_setprio(1);                                            \
    _Pragma("unroll")                                                         \
    for (int mf = 0; mf < 2; ++mf)                                            \
        _Pragma("unroll")                                                     \
        for (int nf = 0; nf < 4; ++nf) {                                      \
            f32x4 c = acc[mf][nf];                                            \
            c = __builtin_amdgcn_mfma_f32_16x16x32_bf16(A_[mf][0], B_[nf][0], c, 0, 0, 0); \
            c = __builtin_amdgcn_mfma_f32_16x16x32_bf16(A_[mf][0], B_[nf][1], c, 0, 0, 0); \
            c = __builtin_amdgcn_mfma_f32_16x16x32_bf16(A_[mf][1], B_[nf][0], c, 0, 0, 0); \
            c = __builtin_amdgcn_mfma_f32_16x16x32_bf16(A_[mf][0], B_[nf][2], c, 0, 0, 0); \
            c = __builtin_amdgcn_mfma_f32_16x16x32_bf16(A_[mf][1], B_[nf][1], c, 0, 0, 0); \
            c = __builtin_amdgcn_mfma_f32_16x16x32_bf16(A_[mf][2], B_[nf][0], c, 0, 0, 0); \
            acc[mf][nf] = c;                                                  \
        }                                                                     \
    __builtin_amdgcn_s_setprio(0);                                            \
    if ((tt) & 1) {                                                           \
        _Pragma("unroll")                                                     \
        for (int mf = 0; mf < 2; ++mf)                                        \
            _Pragma("unroll")                                                 \
            for (int nf = 0; nf < 4; ++nf) {                                  \
                _Pragma("unroll")                                             \
                for (int r = 0; r < 4; ++r)                                   \
                    mst[mf][nf][r] += (double)acc[mf][nf][r];                 \
                acc[mf][nf] = (f32x4){0.f, 0.f, 0.f, 0.f};                    \
            }                                                                 \
    }                                                                         \
    if ((tt) < NT - 2)       { asm volatile("s_waitcnt vmcnt(6)" ::: "memory"); } \
    else if ((tt) == NT - 2) { asm volatile("s_waitcnt vmcnt(0)" ::: "memory"); } \
    BARRIER;                                                                  \
} while (0)

    for (int tb = 0; tb + 3 <= NT; tb += 3) {
        TILE(tb,     0, 2);
        TILE(tb + 1, 1, 0);
        TILE(tb + 2, 2, 1);
    }
    TILE(30, 0, 2);
    TILE(31, 1, 0);
#undef TILE
#undef PB

    // epilogue: bias in f64, store f32, fused column stats
    double* sdsum = (double*)sm;               // [16][128]
    double* sdsqs = sdsum + 16 * 128;          // [16][128]
    const int grp = wm * 4 + hi;               // 0..15 row-group
#pragma unroll
    for (int nf = 0; nf < 4; ++nf) {
        const int colL = wn * 64 + nf * 16 + l15;   // 0..127
        const int colc = col0 + colL;
        const double bb = (double)bias[colc];
        double s = 0.0, q = 0.0;
#pragma unroll
        for (int mf = 0; mf < 2; ++mf)
#pragma unroll
            for (int r = 0; r < 4; ++r) {
                const int roww = row0 + wm * 32 + mf * 16 + hi * 4 + r;
                const float yval = (float)(mst[mf][nf][r] + bb);
                Y[(size_t)roww * NF + colc] = yval;
                s += (double)yval;
                q += (double)yval * (double)yval;
            }
        sdsum[grp * 128 + colL] = s;
        sdsqs[grp * 128 + colL] = q;
    }
    __syncthreads();
    if (t < 128) {
        double s = 0.0;
#pragma unroll
        for (int g = 0; g < 16; ++g) s += sdsum[g * 128 + t];
        atomicAdd(&dsum[col0 + t], s);
    } else if (t < 256) {
        const int c = t - 128;
        double q = 0.0;
#pragma unroll
        for (int g = 0; g < 16; ++g) q += sdsqs[g * 128 + c];
        atomicAdd(&dsqs[col0 + c], q);
    }
}

// ---------------------------------------------------------------------------
// Kernel 2 (fallback, ws too small): in-kernel split, 6 products (R7 code).
// ---------------------------------------------------------------------------
__global__ __launch_bounds__(512) void gemm_mfma_split(
    const float* __restrict__ X, const float* __restrict__ W,
    const int* __restrict__ Mk, const float* __restrict__ bias,
    float* __restrict__ Y)
{
    __shared__ __align__(16) ushort a0s[128 * 40];
    __shared__ __align__(16) ushort a1s[128 * 40];
    __shared__ __align__(16) ushort a2s[128 * 40];
    __shared__ __align__(16) ushort b0s[128 * 40];
    __shared__ __align__(16) ushort b1s[128 * 40];
    __shared__ __align__(16) ushort b2s[128 * 40];

    const int t = threadIdx.x;
    const int row0 = blockIdx.y * 128;
    const int col0 = blockIdx.x * 128;
    const int srow = t >> 2;
    const int skb  = (t & 3) * 8;

    const float* Xp = X + (size_t)(row0 + srow) * INF + skb;
    const float* Wp = W + (size_t)(col0 + srow) * INF + skb;
    const int*   Mp = Mk + (size_t)(col0 + srow) * INF + skb;

    const int l   = t & 63;
    const int l15 = l & 15;
    const int hi  = l >> 4;
    const int wid = t >> 6;
    const int wm  = wid >> 1;
    const int wn  = wid & 1;

    f32x4  acc[2][4];
    double sh[2][4][4];
#pragma unroll
    for (int mf = 0; mf < 2; ++mf)
#pragma unroll
        for (int nf = 0; nf < 4; ++nf) {
            acc[mf][nf] = (f32x4){0.f, 0.f, 0.f, 0.f};
#pragma unroll
            for (int r = 0; r < 4; ++r) sh[mf][nf][r] = 0.0;
        }

    float4 xA0 = *(const float4*)(Xp);
    float4 xA1 = *(const float4*)(Xp + 4);
    float4 wB0 = *(const float4*)(Wp);
    float4 wB1 = *(const float4*)(Wp + 4);
    int4   mB0 = *(const int4*)(Mp);
    int4   mB1 = *(const int4*)(Mp + 4);

    for (int k0 = 0; k0 < INF; k0 += 32) {
        __syncthreads();
        {
            const float v[8] = {xA0.x, xA0.y, xA0.z, xA0.w, xA1.x, xA1.y, xA1.z, xA1.w};
            short8v s0, s1, s2;
#pragma unroll
            for (int i = 0; i < 8; ++i) {
                ushort h0, h1, h2;
                split3(v[i], h0, h1, h2);
                s0[i] = (short)h0; s1[i] = (short)h1; s2[i] = (short)h2;
            }
            const int off = srow * 40 + skb;
            *(short8v*)&a0s[off] = s0;
            *(short8v*)&a1s[off] = s1;
            *(short8v*)&a2s[off] = s2;
        }
        {
            const float wv[8] = {wB0.x * (float)mB0.x, wB0.y * (float)mB0.y,
                                 wB0.z * (float)mB0.z, wB0.w * (float)mB0.w,
                                 wB1.x * (float)mB1.x, wB1.y * (float)mB1.y,
                                 wB1.z * (float)mB1.z, wB1.w * (float)mB1.w};
            short8v s0, s1, s2;
#pragma unroll
            for (int i = 0; i < 8; ++i) {
                ushort h0, h1, h2;
                split3(wv[i], h0, h1, h2);
                s0[i] = (short)h0; s1[i] = (short)h1; s2[i] = (short)h2;
            }
            const int off = srow * 40 + skb;
            *(short8v*)&b0s[off] = s0;
            *(short8v*)&b1s[off] = s1;
            *(short8v*)&b2s[off] = s2;
        }
        __syncthreads();

        if (k0 + 32 < INF) {
            const int kn = k0 + 32;
            xA0 = *(const float4*)(Xp + kn);
            xA1 = *(const float4*)(Xp + kn + 4);
            wB0 = *(const float4*)(Wp + kn);
            wB1 = *(const float4*)(Wp + kn + 4);
            mB0 = *(const int4*)(Mp + kn);
            mB1 = *(const int4*)(Mp + kn + 4);
        }

        short8v A[2][3], B[4][3];
#pragma unroll
        for (int mf = 0; mf < 2; ++mf) {
            const int roff = (wm * 32 + mf * 16 + l15) * 40 + hi * 8;
            A[mf][0] = *(const short8v*)&a0s[roff];
            A[mf][1] = *(const short8v*)&a1s[roff];
            A[mf][2] = *(const short8v*)&a2s[roff];
        }
#pragma unroll
        for (int nf = 0; nf < 4; ++nf) {
            const int roff = (wn * 64 + nf * 16 + l15) * 40 + hi * 8;
            B[nf][0] = *(const short8v*)&b0s[roff];
            B[nf][1] = *(const short8v*)&b1s[roff];
            B[nf][2] = *(const short8v*)&b2s[roff];
        }

#pragma unroll
        for (int mf = 0; mf < 2; ++mf)
#pragma unroll
            for (int nf = 0; nf < 4; ++nf) {
                f32x4 c = acc[mf][nf];
                c = __builtin_amdgcn_mfma_f32_16x16x32_bf16(A[mf][0], B[nf][0], c, 0, 0, 0);
                c = __builtin_amdgcn_mfma_f32_16x16x32_bf16(A[mf][0], B[nf][1], c, 0, 0, 0);
                c = __builtin_amdgcn_mfma_f32_16x16x32_bf16(A[mf][1], B[nf][0], c, 0, 0, 0);
                c = __builtin_amdgcn_mfma_f32_16x16x32_bf16(A[mf][0], B[nf][2], c, 0, 0, 0);
                c = __builtin_amdgcn_mfma_f32_16x16x32_bf16(A[mf][1], B[nf][1], c, 0, 0, 0);
                c = __builtin_amdgcn_mfma_f32_16x16x32_bf16(A[mf][2], B[nf][0], c, 0, 0, 0);
                acc[mf][nf] = c;
            }

        if (k0 & 32) {
#pragma unroll
            for (int mf = 0; mf < 2; ++mf)
#pragma unroll
                for (int nf = 0; nf < 4; ++nf) {
#pragma unroll
                    for (int r = 0; r < 4; ++r) sh[mf][nf][r] += (double)acc[mf][nf][r];
                    acc[mf][nf] = (f32x4){0.f, 0.f, 0.f, 0.f};
                }
        }
    }

#pragma unroll
    for (int mf = 0; mf < 2; ++mf)
#pragma unroll
        for (int nf = 0; nf < 4; ++nf) {
            const int col = col0 + wn * 64 + nf * 16 + l15;
            const double bb = (double)bias[col];
#pragma unroll
            for (int r = 0; r < 4; ++r) {
                const int row = row0 + wm * 32 + mf * 16 + hi * 4 + r;
                Y[(size_t)row * NF + col] = (float)(sh[mf][nf][r] + bb);
            }
        }
}

// ---------------------------------------------------------------------------
// Kernel 3 (fallback path only): per-column partial sums (f64)
// ---------------------------------------------------------------------------
__global__ __launch_bounds__(256) void stats_partial(
    const float* __restrict__ Y, double* __restrict__ dsum, double* __restrict__ dsqs)
{
    const int col = blockIdx.x * 256 + threadIdx.x;
    const int r0  = blockIdx.y * 256;
    double s = 0.0, ss = 0.0;
    for (int i = 0; i < 256; ++i) {
        const float v = Y[(size_t)(r0 + i) * NF + col];
        s  += (double)v;
        ss += (double)v * (double)v;
    }
    atomicAdd(&dsum[col], s);
    atomicAdd(&dsqs[col], ss);
}

// ---------------------------------------------------------------------------
// Kernel 4: finalize mean / rstd / boost (f64 + f32 copies)
// ---------------------------------------------------------------------------
__global__ __launch_bounds__(256) void stats_final(
    const double* __restrict__ dsum, const double* __restrict__ dsqs,
    const float* __restrict__ duty, const int* __restrict__ kp,
    double* __restrict__ mean64, double* __restrict__ rstd64, double* __restrict__ boost64,
    float* __restrict__ mean32, float* __restrict__ rstd32, float* __restrict__ boost32)
{
    const int c = blockIdx.x * 256 + threadIdx.x;
    const double m   = dsum[c] / (double)BATCH;
    const double var = dsqs[c] / (double)BATCH - m * m;
    const double rs  = 1.0 / sqrt(var + (double)BN_EPS);
    const double td  = (double)(*kp) / (double)NF;
    const double bf  = exp(td - (double)duty[c]);
    mean64[c] = m;  rstd64[c] = rs;  boost64[c] = bf;
    mean32[c] = (float)m; rstd32[c] = (float)rs; boost32[c] = (float)bf;
}

// ---------------------------------------------------------------------------
// Kernel 5 (v3): per-row BN-apply + boosted top-k + f64 band refinement.
// Changes vs R13 (selection result identical):
//  - compaction AFTER pass 1 with LCAP=768 (boundary bin = all values in
//    one exponent range, ~557 expected -> fits; R13's 512 cap overflowed
//    and silently fell back to full scans every pass).
//  - classify+flag merged into ONE pass (flags overwrite keys[]; the rare
//    overflow fallback recomputes key bits from yv*boost -> identical).
// ---------------------------------------------------------------------------
#define BAND 1e-4f
#define MAXCAND 64
#define LCAP 768

__global__ __launch_bounds__(256) void topk_kernel(
    const float* __restrict__ mean32, const float* __restrict__ rstd32,
    const float* __restrict__ boost32,
    const double* __restrict__ mean64, const double* __restrict__ rstd64,
    const double* __restrict__ boost64,
    const int* __restrict__ kp,
    const float* __restrict__ X, const float* __restrict__ W,
    const int* __restrict__ Mk, const float* __restrict__ bias,
    float* __restrict__ Y)
{
    __shared__ float    yv[NF];
    __shared__ unsigned keys[NF];
    __shared__ unsigned hist[256];
    __shared__ unsigned scan[256];
    __shared__ unsigned wtot[4];
    __shared__ unsigned s_bin, s_below;
    __shared__ int      s_cnt;
    __shared__ unsigned lkey[LCAP];
    __shared__ double   red[256];
    __shared__ int      s_ncand, s_H;
    __shared__ int      cand_idx[MAXCAND];
    __shared__ double   cand_val[MAXCAND];
    __shared__ unsigned char cand_pick[MAXCAND];

    const int r = blockIdx.x;
    const int t = threadIdx.x;
    const int K = *kp;
    const int lane = t & 63;
    const int w    = t >> 6;

    // ---- load row, BN, keys (float4 vectorized) ----
    for (int j = 0; j < 4; ++j) {
        const int n = j * 1024 + t * 4;
        const float4 v  = *(const float4*)&Y[(size_t)r * NF + n];
        const float4 mm = *(const float4*)&mean32[n];
        const float4 rs = *(const float4*)&rstd32[n];
        const float4 bo = *(const float4*)&boost32[n];
        const float yb[4] = {(v.x - mm.x) * rs.x, (v.y - mm.y) * rs.y,
                             (v.z - mm.z) * rs.z, (v.w - mm.w) * rs.w};
        const float bsv[4] = {yb[0] * bo.x, yb[1] * bo.y, yb[2] * bo.z, yb[3] * bo.w};
#pragma unroll
        for (int q = 0; q < 4; ++q) {
            yv[n + q] = yb[q];
            unsigned u = __float_as_uint(bsv[q]);
            u ^= (u & 0x80000000u) ? 0xFFFFFFFFu : 0x80000000u;
            keys[n + q] = u;
        }
    }
    __syncthreads();

#define SUFFIX_SCAN() do {                                                    \
    unsigned v_ = hist[t];                                                    \
    _Pragma("unroll")                                                         \
    for (int off_ = 1; off_ < 64; off_ <<= 1) {                               \
        const unsigned o_ = __shfl_down(v_, off_, 64);                        \
        if (lane + off_ < 64) v_ += o_;                                       \
    }                                                                         \
    if (lane == 0) wtot[w] = v_;                                              \
    __syncthreads();                                                          \
    unsigned add_ = 0;                                                        \
    for (int ww_ = w + 1; ww_ < 4; ++ww_) add_ += wtot[ww_];                  \
    scan[t] = v_ + add_;                                                      \
    __syncthreads();                                                          \
} while (0)

    // ---- pass 1: full hist over top byte ----
    hist[t] = 0u;
    __syncthreads();
    for (int j = 0; j < 16; ++j)
        atomicAdd(&hist[keys[j * 256 + t] >> 24], 1u);
    __syncthreads();
    SUFFIX_SCAN();
    int remaining = K;
    if (scan[t] >= (unsigned)remaining &&
        (t == 255 || scan[t + 1] < (unsigned)remaining)) {
        s_bin = (unsigned)t;
        s_below = (t == 255) ? 0u : scan[t + 1];
    }
    if (t == 0) s_cnt = 0;
    __syncthreads();
    const unsigned b1 = s_bin;
    unsigned curval = b1 << 24;
    unsigned curmask = 0xFF000000u;
    remaining -= (int)s_below;
    __syncthreads();

    // ---- compact boundary-bin keys (expected ~550, cap 768) ----
    for (int j = 0; j < 16; ++j) {
        const unsigned u = keys[j * 256 + t];
        if ((u >> 24) == b1) {
            const int slot = atomicAdd(&s_cnt, 1);
            if (slot < LCAP) lkey[slot] = u;
        }
    }
    __syncthreads();
    const bool smallbin = (s_cnt <= LCAP);
    const int cnt = smallbin ? s_cnt : 0;

    // ---- passes 2..4 over compacted list (full-scan fallback) ----
    for (int pass = 2; pass >= 0; --pass) {
        const int sh = pass * 8;
        hist[t] = 0u;
        __syncthreads();
        if (smallbin) {
            for (int i = t; i < cnt; i += 256) {
                const unsigned u = lkey[i];
                if ((u & curmask) == curval)
                    atomicAdd(&hist[(u >> sh) & 255u], 1u);
            }
        } else {
            for (int j = 0; j < 16; ++j) {
                const unsigned u = keys[j * 256 + t];
                if ((u & curmask) == curval)
                    atomicAdd(&hist[(u >> sh) & 255u], 1u);
            }
        }
        __syncthreads();
        SUFFIX_SCAN();
        if (scan[t] >= (unsigned)remaining &&
            (t == 255 || scan[t + 1] < (unsigned)remaining)) {
            s_bin = (unsigned)t;
            s_below = (t == 255) ? 0u : scan[t + 1];
        }
        __syncthreads();
        curval |= (s_bin << sh);
        curmask |= (255u << sh);
        remaining -= (int)s_below;
        __syncthreads();
    }
#undef SUFFIX_SCAN

    const unsigned T = curval;
    const unsigned vT = (T & 0x80000000u) ? (T ^ 0x80000000u) : ~T;
    const float cut32 = __uint_as_float(vT);
    const float cutHi = cut32 + BAND;
    const float cutLo = cut32 - BAND;

    // ---- classify + flag in one pass (flags overwrite keys[]) ----
    if (t == 0) { s_ncand = 0; s_H = 0; }
    __syncthreads();
    int locH = 0;
    for (int j = 0; j < 16; ++j) {
        const int n = j * 256 + t;
        const float b = yv[n] * boost32[n];
        unsigned fl = 0u;
        if (b > cutHi) {
            locH++;
            fl = 1u;
        } else if (b >= cutLo) {
            const int slot = atomicAdd(&s_ncand, 1);
            if (slot < MAXCAND) cand_idx[slot] = n;
        }
        keys[n] = fl;
    }
    atomicAdd(&s_H, locH);
    __syncthreads();
    const int H = s_H;
    const bool overflow = (s_ncand > MAXCAND);
    const int ncand = overflow ? MAXCAND : s_ncand;
    int need = K - H;
    if (need < 0) need = 0;

    if (!overflow) {
        // f64 band refinement: exact recompute of candidates
        for (int c = 0; c < ncand; ++c) {
            const int n = cand_idx[c];
            const float* xr = X + (size_t)r * INF;
            const float* wn = W + (size_t)n * INF;
            const int*   mn = Mk + (size_t)n * INF;
            double s = 0.0;
            for (int i = t; i < INF; i += 256)
                s += (double)xr[i] * (double)(wn[i] * (float)mn[i]);
            red[t] = s;
            __syncthreads();
            for (int off = 128; off > 0; off >>= 1) {
                if (t < off) red[t] += red[t + off];
                __syncthreads();
            }
            if (t == 0) {
                const double y64 = red[0] + (double)bias[n];
                cand_val[c] = (y64 - mean64[n]) * rstd64[n] * boost64[n];
                cand_pick[c] = 0;
            }
            __syncthreads();
        }
        if (t == 0) {
            for (int p = 0; p < need; ++p) {
                int best = -1;
                for (int c = 0; c < ncand; ++c) {
                    if (cand_pick[c]) continue;
                    if (best < 0 || cand_val[c] > cand_val[best] ||
                        (cand_val[c] == cand_val[best] && cand_idx[c] < cand_idx[best]))
                        best = c;
                }
                if (best < 0) break;
                cand_pick[best] = 1;
            }
        }
        __syncthreads();
        if (t < ncand && cand_pick[t]) keys[cand_idx[t]] = 1u;
        __syncthreads();
    } else {
        // fallback: pure f32 stable selection; recompute key bits inline
        const int fneed = remaining;
        unsigned cntk = 0u;
        for (int j = 0; j < 16; ++j) {
            const int n = t * 16 + j;
            unsigned u = __float_as_uint(yv[n] * boost32[n]);
            u ^= (u & 0x80000000u) ? 0xFFFFFFFFu : 0x80000000u;
            cntk += (u == T) ? 1u : 0u;
        }
        scan[t] = cntk;
        __syncthreads();
        for (int off = 1; off < 256; off <<= 1) {
            const unsigned add = (t >= off) ? scan[t - off] : 0u;
            __syncthreads();
            scan[t] += add;
            __syncthreads();
        }
        unsigned rank = scan[t] - cntk;
        for (int j = 0; j < 16; ++j) {
            const int n = t * 16 + j;
            unsigned u = __float_as_uint(yv[n] * boost32[n]);
            u ^= (u & 0x80000000u) ? 0xFFFFFFFFu : 0x80000000u;
            bool sel;
            if (u == T) { sel = ((int)rank < fneed); rank++; }
            else        { sel = (u > T); }
            keys[n] = sel ? 1u : 0u;
        }
        __syncthreads();
    }

    // ---- vectorized in-place write ----
    for (int j = 0; j < 4; ++j) {
        const int n = j * 1024 + t * 4;
        float4 o;
        o.x = keys[n + 0] ? yv[n + 0] : 0.0f;
        o.y = keys[n + 1] ? yv[n + 1] : 0.0f;
        o.z = keys[n + 2] ? yv[n + 2] : 0.0f;
        o.w = keys[n + 3] ? yv[n + 3] : 0.0f;
        *(float4*)&Y[(size_t)r * NF + n] = o;
    }
}

// ---------------------------------------------------------------------------
extern "C" void kernel_launch(void* const* d_in, const int* in_sizes, int n_in,
                              void* d_out, int out_size, void* d_ws, size_t ws_size,
                              hipStream_t stream)
{
    const float* x     = (const float*)d_in[0];
    const float* W     = (const float*)d_in[1];
    const float* b     = (const float*)d_in[2];
    const int*   wmask = (const int*)d_in[3];
    const float* duty  = (const float*)d_in[4];
    const int*   kp    = (const int*)d_in[5];
    float* out = (float*)d_out;

    const size_t SPLIT_X_ELTS = (size_t)3 * BATCH * INF;   // ushorts
    const size_t SPLIT_W_ELTS = (size_t)3 * NF * INF;
    const size_t STATS_BYTES  = (size_t)5 * NF * sizeof(double) + (size_t)3 * NF * sizeof(float);
    const size_t NEED_FAST    = (SPLIT_X_ELTS + SPLIT_W_ELTS) * sizeof(ushort) + STATS_BYTES;
    const bool fast = (ws_size >= NEED_FAST);

    ushort* xs  = (ushort*)d_ws;
    ushort* wsp = xs + SPLIT_X_ELTS;
    char* statbase = fast ? (char*)(wsp + SPLIT_W_ELTS) : (char*)d_ws;

    double* dsum    = (double*)statbase;     // [4096]
    double* dsqs    = dsum + NF;             // [4096]
    double* mean64  = dsqs + NF;             // [4096]
    double* rstd64  = mean64 + NF;           // [4096]
    double* boost64 = rstd64 + NF;           // [4096]
    float*  mean32  = (float*)(boost64 + NF);
    float*  rstd32  = mean32 + NF;
    float*  boost32 = rstd32 + NF;

    if (fast) {
        hipLaunchKernelGGL(prep_kernel, dim3(6144), dim3(256), 0, stream,
                           x, W, wmask, xs, wsp, dsum);
        hipFuncSetAttribute((const void*)gemm_mfma_fuse,
                            hipFuncAttributeMaxDynamicSharedMemorySize, 147456);
        hipLaunchKernelGGL(gemm_mfma_fuse, dim3(NF / 128, BATCH / 128), dim3(512), 147456,
                           stream, xs, wsp, b, out, dsum, dsqs);
    } else {
        hipLaunchKernelGGL(zero_ws, dim3(2 * NF / 256), dim3(256), 0, stream, dsum);
        hipLaunchKernelGGL(gemm_mfma_split, dim3(NF / 128, BATCH / 128), dim3(512), 0, stream,
                           x, W, wmask, b, out);
        hipLaunchKernelGGL(stats_partial, dim3(NF / 256, BATCH / 256), dim3(256), 0, stream,
                           out, dsum, dsqs);
    }

    hipLaunchKernelGGL(stats_final, dim3(NF / 256), dim3(256), 0, stream,
                       dsum, dsqs, duty, kp,
                       mean64, rstd64, boost64, mean32, rstd32, boost32);
    hipLaunchKernelGGL(topk_kernel, dim3(BATCH), dim3(256), 0, stream,
                       mean32, rstd32, boost32, mean64, rstd64, boost64, kp,
                       x, W, wmask, b, out);
}